// Round 2
// baseline (7306.586 us; speedup 1.0000x reference)
//
#include <hip/hip_runtime.h>
#include <hip/hip_bf16.h>
#include <math.h>

#define B   64
#define T   512
#define E   300
#define H   150
#define G3  450   // 3*H
#define DH  300   // 2*H
#define A   128
#define NC  5
#define NCV 30

__constant__ int cK0[NC]  = {0,9,12,18,24};
__constant__ int cKC[NC]  = {9,3,6,6,6};
__constant__ int cTS[9]   = {0,3,6,9,12,18,21,24,27};
__constant__ int cTC[9]   = {3,3,3,3,6,3,3,3,3};
__constant__ int cTCAT[9] = {0,0,0,1,2,3,3,4,4};

// ---------------- K1: stable argsort(-lengths) ----------------
__global__ void k_perm(const int* __restrict__ len, int* __restrict__ perm,
                       int* __restrict__ Lp) {
  __shared__ int sp[B];
  int b = threadIdx.x;
  int lb = len[b];
  int rank = 0;
  for (int j = 0; j < B; j++) {
    int lj = len[j];
    rank += (lj > lb) || (lj == lb && j < b);
  }
  sp[rank] = b;
  __syncthreads();
  perm[b] = sp[b];
  Lp[b] = len[sp[b]];
}

// ---------------- K2: xp = x @ W_ih^T + b_ih (10 sets), T-chunked ----------------
// Backward-direction sets are written ALREADY time-reversed so k_gru reads
// XP rows sequentially (enables T-chunking).
// grid (80, 64*nTt): x = set*8+ntile, y = b*nTt + tile
__global__ __launch_bounds__(256) void k_xp(const float* __restrict__ docs,
    const float* __restrict__ wihf, const float* __restrict__ wihb,
    const float* __restrict__ bihf, const float* __restrict__ bihb,
    const int* __restrict__ perm, const int* __restrict__ Lp,
    float* __restrict__ XP, int tbase, int nTt, int chunkT) {
  const int xz = blockIdx.x;   // 0..79
  const int mt = blockIdx.y;
  const int s = xz >> 3, nt = xz & 7;
  const int c = s >> 1, dir = s & 1;
  const float* W  = (dir ? wihb : wihf) + (size_t)c * G3 * E;
  const float* Bi = (dir ? bihb : bihf) + (size_t)c * G3;
  const int b = mt / nTt, tile = mt - b * nTt;
  const int t0 = tbase + (tile << 6);       // global output-t of tile start
  const int L = Lp[b];
  const int pb = perm[b];
  const float* xdoc = docs + (size_t)pb * T * E;
  __shared__ float As[20][68];
  __shared__ float Bs[20][68];
  const int tid = threadIdx.x;
  const int tx = tid & 15, ty = tid >> 4;
  const int n0 = nt << 6;
  float acc[4][4] = {};
  for (int k0 = 0; k0 < E; k0 += 20) {
#pragma unroll
    for (int i = 0; i < 5; i++) {
      int f = tid + (i << 8);
      int mm = f / 20, ee = f - mm * 20;
      int tg = t0 + mm;
      int src = (dir && tg < L) ? (L - 1 - tg) : tg;
      As[ee][mm] = xdoc[(size_t)src * E + (k0 + ee)];
      int g = n0 + mm;
      Bs[ee][mm] = (g < G3) ? W[(size_t)g * E + (k0 + ee)] : 0.f;
    }
    __syncthreads();
#pragma unroll
    for (int e = 0; e < 20; e++) {
      float av[4], bv[4];
#pragma unroll
      for (int i = 0; i < 4; i++) av[i] = As[e][(ty << 2) + i];
#pragma unroll
      for (int jj = 0; jj < 4; jj++) bv[jj] = Bs[e][(tx << 2) + jj];
#pragma unroll
      for (int i = 0; i < 4; i++)
#pragma unroll
        for (int jj = 0; jj < 4; jj++) acc[i][jj] = fmaf(av[i], bv[jj], acc[i][jj]);
    }
    __syncthreads();
  }
  const size_t base = (size_t)(s * B + b) * chunkT * G3;
  const int lt0 = t0 - tbase;
#pragma unroll
  for (int i = 0; i < 4; i++) {
    int lt = lt0 + (ty << 2) + i;
#pragma unroll
    for (int jj = 0; jj < 4; jj++) {
      int g = n0 + (tx << 2) + jj;
      if (g < G3) XP[base + (size_t)lt * G3 + g] = acc[i][jj] + Bi[g];
    }
  }
}

// ---------------- K3: GRU recurrence, 640 chains, chunked with HST carry ----------------
__global__ __launch_bounds__(512) void k_gru(const float* __restrict__ whf,
    const float* __restrict__ whb, const float* __restrict__ bhf,
    const float* __restrict__ bhb, const int* __restrict__ Lp,
    const float* __restrict__ XP, __hip_bfloat16* __restrict__ HALL,
    float* __restrict__ HST, int tbase, int nsteps, int chunkT) {
  const int bid = blockIdx.x;        // s*64 + b
  const int s = bid >> 6, b = bid & 63;
  const int c = s >> 1, dir = s & 1;
  const float* Whh = (dir ? whb : whf) + (size_t)c * G3 * H;
  const float* Bhh = (dir ? bhb : bhf) + (size_t)c * G3;
  const int L = Lp[b];
  const int tid = threadIdx.x;
  const int j = (tid < G3) ? tid : (G3 - 1);
  float2 w2[75];
  {
    const float2* wr = (const float2*)(Whh + (size_t)j * H);
#pragma unroll
    for (int i = 0; i < 75; i++) w2[i] = wr[i];
  }
  const float bias = Bhh[j];
  __shared__ __align__(16) float hS[152];
  __shared__ float gh[452];
  __shared__ float xs[2][452];
  const float* XPb = XP + (size_t)(s * B + b) * chunkT * G3;
  if (tid < 152) hS[tid] = (tbase == 0) ? 0.f
                           : ((tid < H) ? HST[(size_t)bid * 152 + tid] : 0.f);
  for (int f = tid; f < G3; f += 512) xs[0][f] = XPb[f];
  __syncthreads();
  const size_t hbase = (size_t)(c * B + b) * T * DH + (size_t)dir * H;
  const float2* h2 = (const float2*)hS;
  for (int ts = 0; ts < nsteps; ts++) {
    const int cur = ts & 1;
    if (tid < G3) {
      float a0 = bias, a1 = 0.f, a2 = 0.f, a3 = 0.f;
#pragma unroll
      for (int i = 0; i < 72; i += 4) {
        float2 h0 = h2[i + 0]; a0 = fmaf(w2[i + 0].x, h0.x, a0); a0 = fmaf(w2[i + 0].y, h0.y, a0);
        float2 h1 = h2[i + 1]; a1 = fmaf(w2[i + 1].x, h1.x, a1); a1 = fmaf(w2[i + 1].y, h1.y, a1);
        float2 hv2 = h2[i + 2]; a2 = fmaf(w2[i + 2].x, hv2.x, a2); a2 = fmaf(w2[i + 2].y, hv2.y, a2);
        float2 h3 = h2[i + 3]; a3 = fmaf(w2[i + 3].x, h3.x, a3); a3 = fmaf(w2[i + 3].y, h3.y, a3);
      }
      {
        float2 hv;
        hv = h2[72]; a0 = fmaf(w2[72].x, hv.x, a0); a0 = fmaf(w2[72].y, hv.y, a0);
        hv = h2[73]; a1 = fmaf(w2[73].x, hv.x, a1); a1 = fmaf(w2[73].y, hv.y, a1);
        hv = h2[74]; a2 = fmaf(w2[74].x, hv.x, a2); a2 = fmaf(w2[74].y, hv.y, a2);
      }
      gh[j] = (a0 + a1) + (a2 + a3);
    } else if (ts + 1 < nsteps) {
      const float* xr = XPb + (size_t)(ts + 1) * G3;
      for (int f = tid - G3; f < G3; f += (512 - G3)) xs[cur ^ 1][f] = xr[f];
    }
    __syncthreads();
    if (tid < H) {
      const float xr_ = xs[cur][tid], xz_ = xs[cur][H + tid], xn_ = xs[cur][2 * H + tid];
      const float hr_ = gh[tid], hz_ = gh[H + tid], hnn = gh[2 * H + tid];
      const float r = 1.f / (1.f + expf(-(xr_ + hr_)));
      const float z = 1.f / (1.f + expf(-(xz_ + hz_)));
      const float n = tanhf(fmaf(r, hnn, xn_));
      const float hnew = fmaf(z, hS[tid] - n, n);  // (1-z)*n + z*h
      hS[tid] = hnew;
      const int t = tbase + ts;
      const int tout = dir ? ((t < L) ? (L - 1 - t) : t) : t;
      HALL[hbase + (size_t)tout * DH + tid] = __float2bfloat16(hnew);
    }
    __syncthreads();
  }
  if (tid < H) HST[(size_t)bid * 152 + tid] = hS[tid];
}

// ---------------- K4: fused LN + u=tanh(hn@W_s^T+b) + E = u@cv^T ----------------
// grid (2048, 5): x = 16-row m-tile, y = channel. LDS ~38.6KB.
__global__ __launch_bounds__(256) void k_fuse(const __hip_bfloat16* __restrict__ HALL,
    const float* __restrict__ gamma, const float* __restrict__ beta,
    const float* __restrict__ saw, const float* __restrict__ sab,
    const float* __restrict__ cvw, float* __restrict__ Ebuf) {
  const int mt = blockIdx.x;   // 0..2047
  const int c = blockIdx.y;
  const int b = mt >> 5, t0 = (mt & 31) << 4;
  const __hip_bfloat16* hrow = HALL + ((size_t)(c * B + b) * T + t0) * DH;
  __shared__ float hn_s[16][304];
  __shared__ float mu_s[16], rs_s[16];
  __shared__ float Bs[20][132];
  __shared__ float U_s[16][132];
  const int tid = threadIdx.x;
  for (int f = tid; f < 16 * DH; f += 256) {
    int r = f / DH, e = f - r * DH;
    hn_s[r][e] = __bfloat162float(hrow[(size_t)r * DH + e]);
  }
  __syncthreads();
  {
    int r = tid >> 4, l = tid & 15;
    float sm = 0.f, sq = 0.f;
    for (int e = l; e < DH; e += 16) { float v = hn_s[r][e]; sm += v; sq += v * v; }
    sm += __shfl_xor(sm, 1); sm += __shfl_xor(sm, 2); sm += __shfl_xor(sm, 4); sm += __shfl_xor(sm, 8);
    sq += __shfl_xor(sq, 1); sq += __shfl_xor(sq, 2); sq += __shfl_xor(sq, 4); sq += __shfl_xor(sq, 8);
    if (l == 0) {
      float mu = sm * (1.f / 300.f);
      float var = fmaxf(sq * (1.f / 300.f) - mu * mu, 0.f);
      mu_s[r] = mu; rs_s[r] = rsqrtf(var + 1e-5f);
    }
  }
  __syncthreads();
  for (int f = tid; f < 16 * DH; f += 256) {
    int r = f / DH, e = f - r * DH;
    hn_s[r][e] = (hn_s[r][e] - mu_s[r]) * rs_s[r] * gamma[c * DH + e] + beta[c * DH + e];
  }
  __syncthreads();
  const int tx = tid & 31, ty = tid >> 5;   // ty 0..7 -> 2 rows each
  float acc[2][4] = {};
  for (int k0 = 0; k0 < DH; k0 += 20) {
    for (int f = tid; f < 20 * A; f += 256) {
      int n = f / 20, e = f - n * 20;
      Bs[e][n] = saw[((size_t)c * A + n) * DH + k0 + e];
    }
    __syncthreads();
#pragma unroll
    for (int e = 0; e < 20; e++) {
      float av[2], bv[4];
#pragma unroll
      for (int i = 0; i < 2; i++) av[i] = hn_s[(ty << 1) + i][k0 + e];
#pragma unroll
      for (int jj = 0; jj < 4; jj++) bv[jj] = Bs[e][(tx << 2) + jj];
#pragma unroll
      for (int i = 0; i < 2; i++)
#pragma unroll
        for (int jj = 0; jj < 4; jj++) acc[i][jj] = fmaf(av[i], bv[jj], acc[i][jj]);
    }
    __syncthreads();
  }
#pragma unroll
  for (int i = 0; i < 2; i++)
#pragma unroll
    for (int jj = 0; jj < 4; jj++)
      U_s[(ty << 1) + i][(tx << 2) + jj] = tanhf(acc[i][jj] + sab[c * A + (tx << 2) + jj]);
  __syncthreads();
  const int kc = cKC[c], k0c = cK0[c];
  for (int idx = tid; idx < 16 * kc; idx += 256) {
    int r = idx / kc, kk = idx - r * kc;
    const float* cv = cvw + (size_t)(k0c + kk) * A;
    float e = 0.f;
#pragma unroll 4
    for (int a = 0; a < A; a++) e = fmaf(U_s[r][a], cv[a], e);
    Ebuf[((size_t)(k0c + kk) * B + b) * T + t0 + r] = e;
  }
}

// ---------------- K5: masked softmax over t per (k,b) ----------------
__global__ __launch_bounds__(256) void k_soft(const float* __restrict__ Ebuf,
    const int* __restrict__ Lp, float* __restrict__ ATT) {
  const int k = blockIdx.x >> 6, b = blockIdx.x & 63;
  const int L = Lp[b];
  const float* er = Ebuf + ((size_t)k * B + b) * T;
  float* ar = ATT + ((size_t)k * B + b) * T;
  const int tid = threadIdx.x;
  float v0 = (tid < L) ? er[tid] : -1e30f;
  float v1 = (tid + 256 < L) ? er[tid + 256] : -1e30f;
  float mx = fmaxf(v0, v1);
  __shared__ float red[4];
  __shared__ float red2[4];
#pragma unroll
  for (int off = 32; off; off >>= 1) mx = fmaxf(mx, __shfl_xor(mx, off));
  if ((tid & 63) == 0) red[tid >> 6] = mx;
  __syncthreads();
  mx = fmaxf(fmaxf(red[0], red[1]), fmaxf(red[2], red[3]));
  float e0 = (tid < L) ? expf(v0 - mx) : 0.f;
  float e1 = (tid + 256 < L) ? expf(v1 - mx) : 0.f;
  float sm = e0 + e1;
#pragma unroll
  for (int off = 32; off; off >>= 1) sm += __shfl_xor(sm, off);
  if ((tid & 63) == 0) red2[tid >> 6] = sm;
  __syncthreads();
  sm = red2[0] + red2[1] + red2[2] + red2[3];
  const float inv = 1.f / sm;
  ar[tid] = e0 * inv;
  ar[tid + 256] = e1 * inv;
}

// ---------------- K6: docv[k,b,d] = sum_t att[k,b,t] * h4[b,t,d] ----------------
__global__ __launch_bounds__(256) void k_docv(const __hip_bfloat16* __restrict__ HALL,
    const float* __restrict__ ATT, float* __restrict__ DOCV) {
  const int dt = blockIdx.x, b = blockIdx.y;
  const int d0 = dt << 6;
  const int tid = threadIdx.x, tx = tid & 63, ky = tid >> 6;
  const __hip_bfloat16* hb_ = HALL + ((size_t)(4 * B + b) * T) * DH;
  __shared__ float h_s[64][65];
  __shared__ float att_s[30][66];
  float acc[8] = {};
  const int d = d0 + tx;
  for (int t0 = 0; t0 < T; t0 += 64) {
    for (int f = tid; f < 64 * 64; f += 256) {
      int ttt = f >> 6, dl = f & 63;
      h_s[ttt][dl] = (d0 + dl < DH)
          ? __bfloat162float(hb_[(size_t)(t0 + ttt) * DH + d0 + dl]) : 0.f;
    }
    for (int f = tid; f < 30 * 64; f += 256) {
      int kk = f >> 6, ttt = f & 63;
      att_s[kk][ttt] = ATT[((size_t)kk * B + b) * T + t0 + ttt];
    }
    __syncthreads();
    for (int ttt = 0; ttt < 64; ttt++) {
      float hv = h_s[ttt][tx];
#pragma unroll
      for (int i = 0; i < 8; i++) {
        int kk = ky + (i << 2);
        if (kk < 30) acc[i] = fmaf(att_s[kk][ttt], hv, acc[i]);
      }
    }
    __syncthreads();
  }
  if (d < DH) {
#pragma unroll
    for (int i = 0; i < 8; i++) {
      int kk = ky + (i << 2);
      if (kk < 30) DOCV[((size_t)kk * B + b) * DH + d] = acc[i];
    }
  }
}

// ---------------- K7: group attention + output ----------------
__global__ __launch_bounds__(64) void k_group(const float* __restrict__ DOCV,
    const float* __restrict__ gaw, const float* __restrict__ gab,
    const float* __restrict__ gcv, float* __restrict__ out) {
  const int tt = blockIdx.x / B, b = blockIdx.x % B;
  const int lane = threadIdx.x;
  const int c = cTCAT[tt], cnt = cTC[tt], ks = cTS[tt];
  const float* wrow = gaw + ((size_t)c * 64 + lane) * DH;
  const float gbias = gab[c * 64 + lane];
  const float cvl = gcv[tt * 64 + lane];
  float accd[5] = {0, 0, 0, 0, 0};
  float wsum = 0.f;
  for (int n = 0; n < cnt; n++) {
    const float* drow = DOCV + ((size_t)(ks + n) * B + b) * DH;
    float g = 0.f;
    for (int dd = 0; dd < DH; dd++) g = fmaf(drow[dd], wrow[dd], g);
    g += gbias;
    float p = g * cvl;
#pragma unroll
    for (int off = 32; off; off >>= 1) p += __shfl_xor(p, off);
    float w = expf(tanhf(p));
    wsum += w;
#pragma unroll
    for (int i = 0; i < 5; i++) {
      int dd = lane + (i << 6);
      if (dd < DH) accd[i] = fmaf(w, drow[dd], accd[i]);
    }
  }
  const float inv = 1.f / wsum;
  float* orow = out + ((size_t)tt * B + b) * DH;
#pragma unroll
  for (int i = 0; i < 5; i++) {
    int dd = lane + (i << 6);
    if (dd < DH) orow[dd] = accd[i] * inv;
  }
}

extern "C" void kernel_launch(void* const* d_in, const int* in_sizes, int n_in,
                              void* d_out, int out_size, void* d_ws, size_t ws_size,
                              hipStream_t stream) {
  const float* docs = (const float*)d_in[0];
  const int* lens = (const int*)d_in[1];
  const float* wihf = (const float*)d_in[2];
  const float* whhf = (const float*)d_in[3];
  const float* bihf = (const float*)d_in[4];
  const float* bhhf = (const float*)d_in[5];
  const float* wihb = (const float*)d_in[6];
  const float* whhb = (const float*)d_in[7];
  const float* bihb = (const float*)d_in[8];
  const float* bhhb = (const float*)d_in[9];
  const float* gam = (const float*)d_in[10];
  const float* bet = (const float*)d_in[11];
  const float* saw = (const float*)d_in[12];
  const float* sab = (const float*)d_in[13];
  const float* gaw = (const float*)d_in[14];
  const float* gab = (const float*)d_in[15];
  const float* cvw = (const float*)d_in[16];
  const float* gcv = (const float*)d_in[17];
  float* out = (float*)d_out;

  char* ws = (char*)d_ws;
  size_t off = 0;
  auto alloc = [&](size_t bytes) { size_t o = off; off = (off + bytes + 255) & ~(size_t)255; return o; };
  int* PERM = (int*)(ws + alloc(64 * 4));
  int* LP   = (int*)(ws + alloc(64 * 4));
  __hip_bfloat16* HALL = (__hip_bfloat16*)(ws + alloc((size_t)NC * B * T * DH * 2));
  float* EB   = (float*)(ws + alloc((size_t)NCV * B * T * 4));
  float* ATT  = (float*)(ws + alloc((size_t)NCV * B * T * 4));
  float* DOCV = (float*)(ws + alloc((size_t)NCV * B * DH * 4));
  float* HST  = (float*)(ws + alloc((size_t)640 * 152 * 4));
  size_t fixed = off;

  // pick largest chunkT whose XP buffer fits the remaining workspace
  int chunkT = 64;
  for (int cT = 512; cT >= 64; cT >>= 1) {
    size_t xpb = (size_t)10 * B * cT * G3 * 4;
    if (fixed + xpb <= ws_size) { chunkT = cT; break; }
  }
  float* XP = (float*)(ws + fixed);
  const int nTt = chunkT >> 6;

  hipLaunchKernelGGL(k_perm, dim3(1), dim3(64), 0, stream, lens, PERM, LP);
  for (int tbase = 0; tbase < T; tbase += chunkT) {
    hipLaunchKernelGGL(k_xp, dim3(80, 64 * nTt), dim3(256), 0, stream,
                       docs, wihf, wihb, bihf, bihb, PERM, LP, XP, tbase, nTt, chunkT);
    hipLaunchKernelGGL(k_gru, dim3(640), dim3(512), 0, stream,
                       whhf, whhb, bhhf, bhhb, LP, XP, HALL, HST, tbase, chunkT, chunkT);
  }
  hipLaunchKernelGGL(k_fuse, dim3(2048, 5), dim3(256), 0, stream,
                     HALL, gam, bet, saw, sab, cvw, EB);
  hipLaunchKernelGGL(k_soft, dim3(1920), dim3(256), 0, stream, EB, LP, ATT);
  hipLaunchKernelGGL(k_docv, dim3(5, 64), dim3(256), 0, stream, HALL, ATT, DOCV);
  hipLaunchKernelGGL(k_group, dim3(576), dim3(64), 0, stream, DOCV, gaw, gab, gcv, out);
}

// Round 3
// 3698.583 us; speedup vs baseline: 1.9755x; 1.9755x over previous
//
#include <hip/hip_runtime.h>
#include <hip/hip_bf16.h>
#include <math.h>

#define B   64
#define T   512
#define E   300
#define H   150
#define G3  450   // 3*H
#define DH  300   // 2*H
#define A   128
#define NC  5
#define NCV 30

__constant__ int cK0[NC]  = {0,9,12,18,24};
__constant__ int cKC[NC]  = {9,3,6,6,6};
__constant__ int cTS[9]   = {0,3,6,9,12,18,21,24,27};
__constant__ int cTC[9]   = {3,3,3,3,6,3,3,3,3};
__constant__ int cTCAT[9] = {0,0,0,1,2,3,3,4,4};

typedef __attribute__((ext_vector_type(8))) short short8v;
typedef __attribute__((ext_vector_type(4))) float f32x4;

__device__ __forceinline__ short f2bf(float v) {
  unsigned u = __builtin_bit_cast(unsigned, v);
  u += 0x7FFFu + ((u >> 16) & 1u);
  return (short)(u >> 16);
}
__device__ __forceinline__ float bf2f(short s) {
  unsigned u = ((unsigned)(unsigned short)s) << 16;
  return __builtin_bit_cast(float, u);
}

// ---------------- K1: stable argsort(-lengths) ----------------
__global__ void k_perm(const int* __restrict__ len, int* __restrict__ perm,
                       int* __restrict__ Lp) {
  __shared__ int sp[B];
  int b = threadIdx.x;
  int lb = len[b];
  int rank = 0;
  for (int j = 0; j < B; j++) {
    int lj = len[j];
    rank += (lj > lb) || (lj == lb && j < b);
  }
  sp[rank] = b;
  __syncthreads();
  perm[b] = sp[b];
  Lp[b] = len[sp[b]];
}

// ---------------- K2: xp = x @ W_ih^T + b_ih (10 sets), T-chunked ----------------
__global__ __launch_bounds__(256) void k_xp(const float* __restrict__ docs,
    const float* __restrict__ wihf, const float* __restrict__ wihb,
    const float* __restrict__ bihf, const float* __restrict__ bihb,
    const int* __restrict__ perm, const int* __restrict__ Lp,
    float* __restrict__ XP, int tbase, int nTt, int chunkT) {
  const int xz = blockIdx.x;   // 0..79
  const int mt = blockIdx.y;
  const int s = xz >> 3, nt = xz & 7;
  const int c = s >> 1, dir = s & 1;
  const float* W  = (dir ? wihb : wihf) + (size_t)c * G3 * E;
  const float* Bi = (dir ? bihb : bihf) + (size_t)c * G3;
  const int b = mt / nTt, tile = mt - b * nTt;
  const int t0 = tbase + (tile << 6);
  const int L = Lp[b];
  const int pb = perm[b];
  const float* xdoc = docs + (size_t)pb * T * E;
  __shared__ float As[20][68];
  __shared__ float Bs[20][68];
  const int tid = threadIdx.x;
  const int tx = tid & 15, ty = tid >> 4;
  const int n0 = nt << 6;
  float acc[4][4] = {};
  for (int k0 = 0; k0 < E; k0 += 20) {
#pragma unroll
    for (int i = 0; i < 5; i++) {
      int f = tid + (i << 8);
      int mm = f / 20, ee = f - mm * 20;
      int tg = t0 + mm;
      int src = (dir && tg < L) ? (L - 1 - tg) : tg;
      As[ee][mm] = xdoc[(size_t)src * E + (k0 + ee)];
      int g = n0 + mm;
      Bs[ee][mm] = (g < G3) ? W[(size_t)g * E + (k0 + ee)] : 0.f;
    }
    __syncthreads();
#pragma unroll
    for (int e = 0; e < 20; e++) {
      float av[4], bv[4];
#pragma unroll
      for (int i = 0; i < 4; i++) av[i] = As[e][(ty << 2) + i];
#pragma unroll
      for (int jj = 0; jj < 4; jj++) bv[jj] = Bs[e][(tx << 2) + jj];
#pragma unroll
      for (int i = 0; i < 4; i++)
#pragma unroll
        for (int jj = 0; jj < 4; jj++) acc[i][jj] = fmaf(av[i], bv[jj], acc[i][jj]);
    }
    __syncthreads();
  }
  const size_t base = (size_t)(s * B + b) * chunkT * G3;
  const int lt0 = t0 - tbase;
#pragma unroll
  for (int i = 0; i < 4; i++) {
    int lt = lt0 + (ty << 2) + i;
#pragma unroll
    for (int jj = 0; jj < 4; jj++) {
      int g = n0 + (tx << 2) + jj;
      if (g < G3) XP[base + (size_t)lt * G3 + g] = acc[i][jj] + Bi[g];
    }
  }
}

// ---------------- K3: GRU via MFMA. grid 40 = 10 sets x 4 batch-tiles ----------------
// Per block: 16 batches, all 450 gates. W_hh lives in registers as MFMA B-frags.
// h kept fp32 in registers (per activation thread), fed to MFMA as bf16 hi+lo.
__global__ __launch_bounds__(512, 2) void k_gru(const float* __restrict__ whf,
    const float* __restrict__ whb, const float* __restrict__ bhf,
    const float* __restrict__ bhb, const int* __restrict__ Lp,
    const float* __restrict__ XP, __hip_bfloat16* __restrict__ HALL,
    float* __restrict__ HST, int tbase, int nsteps, int chunkT) {
  const int blk = blockIdx.x;         // 0..39
  const int s = blk >> 2, bt = blk & 3;
  const int b0 = bt << 4;
  const int c = s >> 1, dir = s & 1;
  const float* Whh = (dir ? whb : whf) + (size_t)c * G3 * H;
  const float* Bhh = (dir ? bhb : bhf) + (size_t)c * G3;
  const int tid = threadIdx.x, lane = tid & 63, wid = tid >> 6;
  const int l15 = lane & 15, kg = lane >> 4;

  __shared__ float gh[16][464];
  __shared__ short hfH[16][168];   // 336B row stride: 16B aligned for b128
  __shared__ short hfL[16][168];

  // ---- persistent W fragments: 4 N-tiles/wave x 5 K-slices ----
  short8v Wf[4][5];
  float bias[4];
#pragma unroll
  for (int r = 0; r < 4; r++) {
    int tile = wid + 8 * r;
    int gate = tile * 16 + l15;
    bool gv = (tile < 29) && (gate < G3);
    bias[r] = gv ? Bhh[gate] : 0.f;
#pragma unroll
    for (int sl = 0; sl < 5; sl++) {
      short8v w = {};
      if (gv) {
        int k0 = sl * 32 + kg * 8;
#pragma unroll
        for (int j = 0; j < 8; j++) {
          int k = k0 + j;
          if (k < H) w[j] = f2bf(Whh[(size_t)gate * H + k]);
        }
      }
      Wf[r][sl] = w;
    }
  }

  // ---- activation-thread setup: 5 items (b,j) per thread ----
  bool live[5]; float hq[5]; int Lq[5], ghoff[5], hfoff[5];
  size_t xpo[5], ho[5];
#pragma unroll
  for (int q = 0; q < 5; q++) {
    int i = tid + 512 * q;
    live[q] = (i < 2400);
    int bl = live[q] ? (i / 150) : 0;
    int j  = live[q] ? (i - bl * 150) : 0;
    int bg = b0 + bl;
    Lq[q] = Lp[bg];
    ghoff[q] = bl * 464 + j;
    hfoff[q] = bl * 168 + j;
    xpo[q] = ((size_t)(s * B + bg) * chunkT) * G3 + j;
    ho[q]  = ((size_t)(c * B + bg) * T) * DH + (size_t)dir * H + j;
    hq[q] = 0.f;
    if (tbase > 0 && live[q]) hq[q] = HST[(size_t)(s * B + bg) * 152 + j];
  }

  // zero the k>=150 pad of hfrag, write initial h
  for (int f = tid; f < 16 * 168; f += 512) {
    int kk = f % 168;
    if (kk >= H) { ((short*)hfH)[f] = 0; ((short*)hfL)[f] = 0; }
  }
#pragma unroll
  for (int q = 0; q < 5; q++) if (live[q]) {
    short hi = f2bf(hq[q]); float rem = hq[q] - bf2f(hi);
    ((short*)hfH)[hfoff[q]] = hi; ((short*)hfL)[hfoff[q]] = f2bf(rem);
  }
  // prefetch XP row 0
  float xr_[5], xz_[5], xn_[5];
#pragma unroll
  for (int q = 0; q < 5; q++) {
    const float* p = XP + xpo[q];
    xr_[q] = p[0]; xz_[q] = p[H]; xn_[q] = p[2 * H];
  }
  __syncthreads();

  for (int ts = 0; ts < nsteps; ts++) {
    // ---- P1: MFMA gh = [h_hi + h_lo] @ W^T + bias ----
    f32x4 acc[4];
#pragma unroll
    for (int r = 0; r < 4; r++) acc[r] = f32x4{bias[r], bias[r], bias[r], bias[r]};
#pragma unroll
    for (int sl = 0; sl < 5; sl++) {
      int k0 = sl * 32 + kg * 8;
      short8v ah = *(const short8v*)&hfH[l15][k0];
      short8v al = *(const short8v*)&hfL[l15][k0];
#pragma unroll
      for (int r = 0; r < 4; r++) {
        acc[r] = __builtin_amdgcn_mfma_f32_16x16x32_bf16(ah, Wf[r][sl], acc[r], 0, 0, 0);
        acc[r] = __builtin_amdgcn_mfma_f32_16x16x32_bf16(al, Wf[r][sl], acc[r], 0, 0, 0);
      }
    }
#pragma unroll
    for (int r = 0; r < 4; r++) {
      int tile = wid + 8 * r;
      if (tile < 29) {
#pragma unroll
        for (int v = 0; v < 4; v++) gh[kg * 4 + v][tile * 16 + l15] = acc[r][v];
      }
    }
    __syncthreads();
    // ---- P2: activation + h update + hfrag write ----
    const int t = tbase + ts;
#pragma unroll
    for (int q = 0; q < 5; q++) if (live[q]) {
      const float* g = (const float*)gh + ghoff[q];
      float ghr = g[0], ghz = g[H], ghn = g[2 * H];
      float r = 1.f / (1.f + __expf(-(xr_[q] + ghr)));
      float z = 1.f / (1.f + __expf(-(xz_[q] + ghz)));
      float ta = fmaf(r, ghn, xn_[q]);
      ta = fminf(fmaxf(ta, -15.f), 15.f);
      float ex = __expf(2.f * ta);
      float n = (ex - 1.f) / (ex + 1.f);
      float hnew = fmaf(z, hq[q] - n, n);
      hq[q] = hnew;
      short hi = f2bf(hnew); float rem = hnew - bf2f(hi);
      ((short*)hfH)[hfoff[q]] = hi; ((short*)hfL)[hfoff[q]] = f2bf(rem);
      int tout = dir ? ((t < Lq[q]) ? (Lq[q] - 1 - t) : t) : t;
      HALL[ho[q] + (size_t)tout * DH] = __float2bfloat16(hnew);
    }
    // prefetch next XP row (register double-duty after last use)
    int tn = (ts + 1 < nsteps) ? ts + 1 : ts;
#pragma unroll
    for (int q = 0; q < 5; q++) {
      const float* p = XP + xpo[q] + (size_t)tn * G3;
      xr_[q] = p[0]; xz_[q] = p[H]; xn_[q] = p[2 * H];
    }
    __syncthreads();
  }
#pragma unroll
  for (int q = 0; q < 5; q++) if (live[q])
    HST[(size_t)(s * B + b0 + (ghoff[q] / 464)) * 152 + (ghoff[q] % 464)] = hq[q];
}

// ---------------- K4: fused LN + u=tanh(hn@W_s^T+b) + E = u@cv^T ----------------
__global__ __launch_bounds__(256) void k_fuse(const __hip_bfloat16* __restrict__ HALL,
    const float* __restrict__ gamma, const float* __restrict__ beta,
    const float* __restrict__ saw, const float* __restrict__ sab,
    const float* __restrict__ cvw, float* __restrict__ Ebuf) {
  const int mt = blockIdx.x;   // 0..2047
  const int c = blockIdx.y;
  const int b = mt >> 5, t0 = (mt & 31) << 4;
  const __hip_bfloat16* hrow = HALL + ((size_t)(c * B + b) * T + t0) * DH;
  __shared__ float hn_s[16][304];
  __shared__ float mu_s[16], rs_s[16];
  __shared__ float Bs[20][132];
  __shared__ float U_s[16][132];
  const int tid = threadIdx.x;
  for (int f = tid; f < 16 * DH; f += 256) {
    int r = f / DH, e = f - r * DH;
    hn_s[r][e] = __bfloat162float(hrow[(size_t)r * DH + e]);
  }
  __syncthreads();
  {
    int r = tid >> 4, l = tid & 15;
    float sm = 0.f, sq = 0.f;
    for (int e = l; e < DH; e += 16) { float v = hn_s[r][e]; sm += v; sq += v * v; }
    sm += __shfl_xor(sm, 1); sm += __shfl_xor(sm, 2); sm += __shfl_xor(sm, 4); sm += __shfl_xor(sm, 8);
    sq += __shfl_xor(sq, 1); sq += __shfl_xor(sq, 2); sq += __shfl_xor(sq, 4); sq += __shfl_xor(sq, 8);
    if (l == 0) {
      float mu = sm * (1.f / 300.f);
      float var = fmaxf(sq * (1.f / 300.f) - mu * mu, 0.f);
      mu_s[r] = mu; rs_s[r] = rsqrtf(var + 1e-5f);
    }
  }
  __syncthreads();
  for (int f = tid; f < 16 * DH; f += 256) {
    int r = f / DH, e = f - r * DH;
    hn_s[r][e] = (hn_s[r][e] - mu_s[r]) * rs_s[r] * gamma[c * DH + e] + beta[c * DH + e];
  }
  __syncthreads();
  const int tx = tid & 31, ty = tid >> 5;
  float acc[2][4] = {};
  for (int k0 = 0; k0 < DH; k0 += 20) {
    for (int f = tid; f < 20 * A; f += 256) {
      int n = f / 20, e = f - n * 20;
      Bs[e][n] = saw[((size_t)c * A + n) * DH + k0 + e];
    }
    __syncthreads();
#pragma unroll
    for (int e = 0; e < 20; e++) {
      float av[2], bv[4];
#pragma unroll
      for (int i = 0; i < 2; i++) av[i] = hn_s[(ty << 1) + i][k0 + e];
#pragma unroll
      for (int jj = 0; jj < 4; jj++) bv[jj] = Bs[e][(tx << 2) + jj];
#pragma unroll
      for (int i = 0; i < 2; i++)
#pragma unroll
        for (int jj = 0; jj < 4; jj++) acc[i][jj] = fmaf(av[i], bv[jj], acc[i][jj]);
    }
    __syncthreads();
  }
#pragma unroll
  for (int i = 0; i < 2; i++)
#pragma unroll
    for (int jj = 0; jj < 4; jj++)
      U_s[(ty << 1) + i][(tx << 2) + jj] = tanhf(acc[i][jj] + sab[c * A + (tx << 2) + jj]);
  __syncthreads();
  const int kc = cKC[c], k0c = cK0[c];
  for (int idx = tid; idx < 16 * kc; idx += 256) {
    int r = idx / kc, kk = idx - r * kc;
    const float* cv = cvw + (size_t)(k0c + kk) * A;
    float e = 0.f;
#pragma unroll 4
    for (int a = 0; a < A; a++) e = fmaf(U_s[r][a], cv[a], e);
    Ebuf[((size_t)(k0c + kk) * B + b) * T + t0 + r] = e;
  }
}

// ---------------- K5: masked softmax over t per (k,b) ----------------
__global__ __launch_bounds__(256) void k_soft(const float* __restrict__ Ebuf,
    const int* __restrict__ Lp, float* __restrict__ ATT) {
  const int k = blockIdx.x >> 6, b = blockIdx.x & 63;
  const int L = Lp[b];
  const float* er = Ebuf + ((size_t)k * B + b) * T;
  float* ar = ATT + ((size_t)k * B + b) * T;
  const int tid = threadIdx.x;
  float v0 = (tid < L) ? er[tid] : -1e30f;
  float v1 = (tid + 256 < L) ? er[tid + 256] : -1e30f;
  float mx = fmaxf(v0, v1);
  __shared__ float red[4];
  __shared__ float red2[4];
#pragma unroll
  for (int off = 32; off; off >>= 1) mx = fmaxf(mx, __shfl_xor(mx, off));
  if ((tid & 63) == 0) red[tid >> 6] = mx;
  __syncthreads();
  mx = fmaxf(fmaxf(red[0], red[1]), fmaxf(red[2], red[3]));
  float e0 = (tid < L) ? expf(v0 - mx) : 0.f;
  float e1 = (tid + 256 < L) ? expf(v1 - mx) : 0.f;
  float sm = e0 + e1;
#pragma unroll
  for (int off = 32; off; off >>= 1) sm += __shfl_xor(sm, off);
  if ((tid & 63) == 0) red2[tid >> 6] = sm;
  __syncthreads();
  sm = red2[0] + red2[1] + red2[2] + red2[3];
  const float inv = 1.f / sm;
  ar[tid] = e0 * inv;
  ar[tid + 256] = e1 * inv;
}

// ---------------- K6: docv[k,b,d] = sum_t att[k,b,t] * h4[b,t,d] ----------------
__global__ __launch_bounds__(256) void k_docv(const __hip_bfloat16* __restrict__ HALL,
    const float* __restrict__ ATT, float* __restrict__ DOCV) {
  const int dt = blockIdx.x, b = blockIdx.y;
  const int d0 = dt << 6;
  const int tid = threadIdx.x, tx = tid & 63, ky = tid >> 6;
  const __hip_bfloat16* hb_ = HALL + ((size_t)(4 * B + b) * T) * DH;
  __shared__ float h_s[64][65];
  __shared__ float att_s[30][66];
  float acc[8] = {};
  const int d = d0 + tx;
  for (int t0 = 0; t0 < T; t0 += 64) {
    for (int f = tid; f < 64 * 64; f += 256) {
      int ttt = f >> 6, dl = f & 63;
      h_s[ttt][dl] = (d0 + dl < DH)
          ? __bfloat162float(hb_[(size_t)(t0 + ttt) * DH + d0 + dl]) : 0.f;
    }
    for (int f = tid; f < 30 * 64; f += 256) {
      int kk = f >> 6, ttt = f & 63;
      att_s[kk][ttt] = ATT[((size_t)kk * B + b) * T + t0 + ttt];
    }
    __syncthreads();
    for (int ttt = 0; ttt < 64; ttt++) {
      float hv = h_s[ttt][tx];
#pragma unroll
      for (int i = 0; i < 8; i++) {
        int kk = ky + (i << 2);
        if (kk < 30) acc[i] = fmaf(att_s[kk][ttt], hv, acc[i]);
      }
    }
    __syncthreads();
  }
  if (d < DH) {
#pragma unroll
    for (int i = 0; i < 8; i++) {
      int kk = ky + (i << 2);
      if (kk < 30) DOCV[((size_t)kk * B + b) * DH + d] = acc[i];
    }
  }
}

// ---------------- K7: group attention + output ----------------
__global__ __launch_bounds__(64) void k_group(const float* __restrict__ DOCV,
    const float* __restrict__ gaw, const float* __restrict__ gab,
    const float* __restrict__ gcv, float* __restrict__ out) {
  const int tt = blockIdx.x / B, b = blockIdx.x % B;
  const int lane = threadIdx.x;
  const int c = cTCAT[tt], cnt = cTC[tt], ks = cTS[tt];
  const float* wrow = gaw + ((size_t)c * 64 + lane) * DH;
  const float gbias = gab[c * 64 + lane];
  const float cvl = gcv[tt * 64 + lane];
  float accd[5] = {0, 0, 0, 0, 0};
  float wsum = 0.f;
  for (int n = 0; n < cnt; n++) {
    const float* drow = DOCV + ((size_t)(ks + n) * B + b) * DH;
    float g = 0.f;
    for (int dd = 0; dd < DH; dd++) g = fmaf(drow[dd], wrow[dd], g);
    g += gbias;
    float p = g * cvl;
#pragma unroll
    for (int off = 32; off; off >>= 1) p += __shfl_xor(p, off);
    float w = expf(tanhf(p));
    wsum += w;
#pragma unroll
    for (int i = 0; i < 5; i++) {
      int dd = lane + (i << 6);
      if (dd < DH) accd[i] = fmaf(w, drow[dd], accd[i]);
    }
  }
  const float inv = 1.f / wsum;
  float* orow = out + ((size_t)tt * B + b) * DH;
#pragma unroll
  for (int i = 0; i < 5; i++) {
    int dd = lane + (i << 6);
    if (dd < DH) orow[dd] = accd[i] * inv;
  }
}

extern "C" void kernel_launch(void* const* d_in, const int* in_sizes, int n_in,
                              void* d_out, int out_size, void* d_ws, size_t ws_size,
                              hipStream_t stream) {
  const float* docs = (const float*)d_in[0];
  const int* lens = (const int*)d_in[1];
  const float* wihf = (const float*)d_in[2];
  const float* whhf = (const float*)d_in[3];
  const float* bihf = (const float*)d_in[4];
  const float* bhhf = (const float*)d_in[5];
  const float* wihb = (const float*)d_in[6];
  const float* whhb = (const float*)d_in[7];
  const float* bihb = (const float*)d_in[8];
  const float* bhhb = (const float*)d_in[9];
  const float* gam = (const float*)d_in[10];
  const float* bet = (const float*)d_in[11];
  const float* saw = (const float*)d_in[12];
  const float* sab = (const float*)d_in[13];
  const float* gaw = (const float*)d_in[14];
  const float* gab = (const float*)d_in[15];
  const float* cvw = (const float*)d_in[16];
  const float* gcv = (const float*)d_in[17];
  float* out = (float*)d_out;

  char* ws = (char*)d_ws;
  size_t off = 0;
  auto alloc = [&](size_t bytes) { size_t o = off; off = (off + bytes + 255) & ~(size_t)255; return o; };
  int* PERM = (int*)(ws + alloc(64 * 4));
  int* LP   = (int*)(ws + alloc(64 * 4));
  __hip_bfloat16* HALL = (__hip_bfloat16*)(ws + alloc((size_t)NC * B * T * DH * 2));
  float* EB   = (float*)(ws + alloc((size_t)NCV * B * T * 4));
  float* ATT  = (float*)(ws + alloc((size_t)NCV * B * T * 4));
  float* DOCV = (float*)(ws + alloc((size_t)NCV * B * DH * 4));
  float* HST  = (float*)(ws + alloc((size_t)640 * 152 * 4));
  size_t fixed = off;

  int chunkT = 64;
  for (int cT = 512; cT >= 64; cT >>= 1) {
    size_t xpb = (size_t)10 * B * cT * G3 * 4;
    if (fixed + xpb <= ws_size) { chunkT = cT; break; }
  }
  float* XP = (float*)(ws + fixed);
  const int nTt = chunkT >> 6;

  hipLaunchKernelGGL(k_perm, dim3(1), dim3(64), 0, stream, lens, PERM, LP);
  for (int tbase = 0; tbase < T; tbase += chunkT) {
    hipLaunchKernelGGL(k_xp, dim3(80, 64 * nTt), dim3(256), 0, stream,
                       docs, wihf, wihb, bihf, bihb, PERM, LP, XP, tbase, nTt, chunkT);
    hipLaunchKernelGGL(k_gru, dim3(40), dim3(512), 0, stream,
                       whhf, whhb, bhhf, bhhb, LP, XP, HALL, HST, tbase, chunkT, chunkT);
  }
  hipLaunchKernelGGL(k_fuse, dim3(2048, 5), dim3(256), 0, stream,
                     HALL, gam, bet, saw, sab, cvw, EB);
  hipLaunchKernelGGL(k_soft, dim3(1920), dim3(256), 0, stream, EB, LP, ATT);
  hipLaunchKernelGGL(k_docv, dim3(5, 64), dim3(256), 0, stream, HALL, ATT, DOCV);
  hipLaunchKernelGGL(k_group, dim3(576), dim3(64), 0, stream, DOCV, gaw, gab, gcv, out);
}

// Round 4
// 2331.905 us; speedup vs baseline: 3.1333x; 1.5861x over previous
//
#include <hip/hip_runtime.h>
#include <hip/hip_bf16.h>
#include <math.h>

#define B   64
#define T   512
#define E   300
#define H   150
#define G3  450   // 3*H
#define DH  300   // 2*H
#define A   128
#define NC  5
#define NCV 30
#define KP  320   // padded K (E and DH both <= 320, 10 slices of 32)
#define LDA 328   // LDS row stride in shorts (2-way bank alias only)

__constant__ int cK0[NC]  = {0,9,12,18,24};
__constant__ int cKC[NC]  = {9,3,6,6,6};
__constant__ int cTS[9]   = {0,3,6,9,12,18,21,24,27};
__constant__ int cTC[9]   = {3,3,3,3,6,3,3,3,3};
__constant__ int cTCAT[9] = {0,0,0,1,2,3,3,4,4};

typedef __attribute__((ext_vector_type(8))) short short8v;
typedef __attribute__((ext_vector_type(4))) short short4v;
typedef __attribute__((ext_vector_type(4))) float f32x4;

__device__ __forceinline__ short f2bf(float v) {
  unsigned u = __builtin_bit_cast(unsigned, v);
  u += 0x7FFFu + ((u >> 16) & 1u);
  return (short)(u >> 16);
}
__device__ __forceinline__ float bf2f(short s) {
  unsigned u = ((unsigned)(unsigned short)s) << 16;
  return __builtin_bit_cast(float, u);
}

// ---------------- K1: stable argsort(-lengths) ----------------
__global__ void k_perm(const int* __restrict__ len, int* __restrict__ perm,
                       int* __restrict__ Lp) {
  __shared__ int sp[B];
  int b = threadIdx.x;
  int lb = len[b];
  int rank = 0;
  for (int j = 0; j < B; j++) {
    int lj = len[j];
    rank += (lj > lb) || (lj == lb && j < b);
  }
  sp[rank] = b;
  __syncthreads();
  perm[b] = sp[b];
  Lp[b] = len[sp[b]];
}

// ---------------- prep: docs -> bf16 hi/lo, padded to KP ----------------
__global__ __launch_bounds__(256) void k_prepx(const float* __restrict__ docs,
    short* __restrict__ DXH, short* __restrict__ DXL) {
  const int total = B * T * (KP / 8);
  for (int i = blockIdx.x * 256 + threadIdx.x; i < total; i += gridDim.x * 256) {
    int bt = i / (KP / 8), q = i - bt * (KP / 8);
    const float* src = docs + (size_t)bt * E + q * 8;
    short8v h{}, l{};
#pragma unroll
    for (int j = 0; j < 8; j++) {
      int e = q * 8 + j;
      float v = (e < E) ? src[j] : 0.f;
      short hi = f2bf(v);
      h[j] = hi; l[j] = f2bf(v - bf2f(hi));
    }
    *(short8v*)(DXH + (size_t)bt * KP + q * 8) = h;
    *(short8v*)(DXL + (size_t)bt * KP + q * 8) = l;
  }
}

// ---------------- prep: Wg = gamma * sent_att_w (hi/lo), sg, cb ----------------
__global__ __launch_bounds__(64) void k_prepw(const float* __restrict__ saw,
    const float* __restrict__ sab, const float* __restrict__ gamma,
    const float* __restrict__ beta, short* __restrict__ WGH,
    short* __restrict__ WGL, float* __restrict__ SG, float* __restrict__ CB) {
  const int blk = blockIdx.x;          // c*128 + a
  const int c = blk >> 7;
  const int lane = threadIdx.x;
  const float* wrow = saw + (size_t)blk * DH;
  float sg = 0.f, cbv = 0.f;
  for (int e = lane; e < KP; e += 64) {
    float wg = 0.f;
    if (e < DH) {
      float w = wrow[e];
      wg = w * gamma[c * DH + e];
      sg += wg;
      cbv += beta[c * DH + e] * w;
    }
    short hi = f2bf(wg);
    WGH[(size_t)blk * KP + e] = hi;
    WGL[(size_t)blk * KP + e] = f2bf(wg - bf2f(hi));
  }
#pragma unroll
  for (int off = 32; off; off >>= 1) { sg += __shfl_xor(sg, off); cbv += __shfl_xor(cbv, off); }
  if (lane == 0) { SG[blk] = sg; CB[blk] = cbv + sab[blk]; }
}

// ---------------- K2: xp via MFMA (3-term hi/lo), T-chunked ----------------
// grid (80, ITot/8): x = s*8 + ntile(64 gates); each block: W-frags in regs, 8 iters.
__global__ __launch_bounds__(256) void k_xp(const short* __restrict__ DXH,
    const short* __restrict__ DXL,
    const float* __restrict__ wihf, const float* __restrict__ wihb,
    const float* __restrict__ bihf, const float* __restrict__ bihb,
    const int* __restrict__ perm, const int* __restrict__ Lp,
    float* __restrict__ XP, int tbase, int nMt, int chunkT) {
  const int xz = blockIdx.x;   // 0..79
  const int s = xz >> 3, nt = xz & 7;
  const int c = s >> 1, dir = s & 1;
  const float* W  = (dir ? wihb : wihf) + (size_t)c * G3 * E;
  const float* Bi = (dir ? bihb : bihf) + (size_t)c * G3;
  const int tid = threadIdx.x, lane = tid & 63, wid = tid >> 6;
  const int l15 = lane & 15, kg = lane >> 4;
  const int gw = nt * 64 + wid * 16 + l15;
  const bool gv = gw < G3;
  const float biasv = gv ? Bi[gw] : 0.f;

  // persistent B-frags (W_ih) hi/lo
  short8v Whi[10], Wlo[10];
#pragma unroll
  for (int sl = 0; sl < 10; sl++) {
    short8v hi{}, lo{};
    if (gv) {
#pragma unroll
      for (int j = 0; j < 8; j++) {
        int k = sl * 32 + kg * 8 + j;
        if (k < E) {
          float w = W[(size_t)gw * E + k];
          short h = f2bf(w);
          hi[j] = h; lo[j] = f2bf(w - bf2f(h));
        }
      }
    }
    Whi[sl] = hi; Wlo[sl] = lo;
  }

  __shared__ short Ah[32 * LDA];
  __shared__ short Al[32 * LDA];

  for (int i = 0; i < 8; i++) {
    const int idx = blockIdx.y * 8 + i;
    const int b = idx / nMt, mtile = idx - b * nMt;
    const int L = Lp[b];
    const int pb = perm[b];
    const int t0g = tbase + mtile * 32;
    // stage A (32 rows of x, hi/lo)
    for (int f = tid; f < 32 * (KP / 8); f += 256) {
      int r = f / (KP / 8), q = f - r * (KP / 8);
      int tg = t0g + r;
      int src = (dir && tg < L) ? (L - 1 - tg) : tg;
      size_t go = ((size_t)pb * T + src) * KP + q * 8;
      *(short8v*)&Ah[r * LDA + q * 8] = *(const short8v*)(DXH + go);
      *(short8v*)&Al[r * LDA + q * 8] = *(const short8v*)(DXL + go);
    }
    __syncthreads();
    f32x4 acc[2];
#pragma unroll
    for (int m2 = 0; m2 < 2; m2++) acc[m2] = f32x4{biasv, biasv, biasv, biasv};
#pragma unroll
    for (int sl = 0; sl < 10; sl++) {
#pragma unroll
      for (int m2 = 0; m2 < 2; m2++) {
        const int ro = (m2 * 16 + l15) * LDA + sl * 32 + kg * 8;
        short8v ah = *(const short8v*)&Ah[ro];
        short8v al = *(const short8v*)&Al[ro];
        acc[m2] = __builtin_amdgcn_mfma_f32_16x16x32_bf16(ah, Whi[sl], acc[m2], 0, 0, 0);
        acc[m2] = __builtin_amdgcn_mfma_f32_16x16x32_bf16(ah, Wlo[sl], acc[m2], 0, 0, 0);
        acc[m2] = __builtin_amdgcn_mfma_f32_16x16x32_bf16(al, Whi[sl], acc[m2], 0, 0, 0);
      }
    }
    if (gv) {
      const size_t base = (size_t)(s * B + b) * chunkT * G3;
#pragma unroll
      for (int m2 = 0; m2 < 2; m2++) {
        const int lt = mtile * 32 + m2 * 16 + kg * 4;
        float* xp = XP + base + (size_t)lt * G3 + gw;
#pragma unroll
        for (int v = 0; v < 4; v++) xp[(size_t)v * G3] = acc[m2][v];
      }
    }
    __syncthreads();
  }
}

// ---------------- K3: GRU via MFMA. grid 40 = 10 sets x 4 batch-tiles ----------------
__global__ __launch_bounds__(512, 1) void k_gru(const float* __restrict__ whf,
    const float* __restrict__ whb, const float* __restrict__ bhf,
    const float* __restrict__ bhb, const int* __restrict__ Lp,
    const float* __restrict__ XP, __hip_bfloat16* __restrict__ HALL,
    float* __restrict__ HST, int tbase, int nsteps, int chunkT) {
  const int blk = blockIdx.x;         // 0..39
  const int s = blk >> 2, bt = blk & 3;
  const int b0 = bt << 4;
  const int c = s >> 1, dir = s & 1;
  const float* Whh = (dir ? whb : whf) + (size_t)c * G3 * H;
  const float* Bhh = (dir ? bhb : bhf) + (size_t)c * G3;
  const int tid = threadIdx.x, lane = tid & 63, wid = tid >> 6;
  const int l15 = lane & 15, kg = lane >> 4;

  __shared__ float gh[16][464];
  __shared__ short hfH[16][168];
  __shared__ short hfL[16][168];

  short8v Wf[4][5];
  float bias[4];
#pragma unroll
  for (int r = 0; r < 4; r++) {
    int tile = wid + 8 * r;
    int gate = tile * 16 + l15;
    bool gv = (tile < 29) && (gate < G3);
    bias[r] = gv ? Bhh[gate] : 0.f;
#pragma unroll
    for (int sl = 0; sl < 5; sl++) {
      short8v w = {};
      if (gv) {
        int k0 = sl * 32 + kg * 8;
#pragma unroll
        for (int j = 0; j < 8; j++) {
          int k = k0 + j;
          if (k < H) w[j] = f2bf(Whh[(size_t)gate * H + k]);
        }
      }
      Wf[r][sl] = w;
    }
  }

  bool live[5]; float hq[5]; int Lq[5], ghoff[5], hfoff[5];
  size_t xpo[5], ho[5];
#pragma unroll
  for (int q = 0; q < 5; q++) {
    int i = tid + 512 * q;
    live[q] = (i < 2400);
    int bl = live[q] ? (i / 150) : 0;
    int j  = live[q] ? (i - bl * 150) : 0;
    int bg = b0 + bl;
    Lq[q] = Lp[bg];
    ghoff[q] = bl * 464 + j;
    hfoff[q] = bl * 168 + j;
    xpo[q] = ((size_t)(s * B + bg) * chunkT) * G3 + j;
    ho[q]  = ((size_t)(c * B + bg) * T) * DH + (size_t)dir * H + j;
    hq[q] = 0.f;
    if (tbase > 0 && live[q]) hq[q] = HST[(size_t)(s * B + bg) * 152 + j];
  }

  for (int f = tid; f < 16 * 168; f += 512) {
    int kk = f % 168;
    if (kk >= H) { ((short*)hfH)[f] = 0; ((short*)hfL)[f] = 0; }
  }
#pragma unroll
  for (int q = 0; q < 5; q++) if (live[q]) {
    short hi = f2bf(hq[q]); float rem = hq[q] - bf2f(hi);
    ((short*)hfH)[hfoff[q]] = hi; ((short*)hfL)[hfoff[q]] = f2bf(rem);
  }
  float xr_[5], xz_[5], xn_[5];
#pragma unroll
  for (int q = 0; q < 5; q++) {
    const float* p = XP + xpo[q];
    xr_[q] = p[0]; xz_[q] = p[H]; xn_[q] = p[2 * H];
  }
  __syncthreads();

  for (int ts = 0; ts < nsteps; ts++) {
    f32x4 acc[4];
#pragma unroll
    for (int r = 0; r < 4; r++) acc[r] = f32x4{bias[r], bias[r], bias[r], bias[r]};
#pragma unroll
    for (int sl = 0; sl < 5; sl++) {
      int k0 = sl * 32 + kg * 8;
      short8v ah = *(const short8v*)&hfH[l15][k0];
      short8v al = *(const short8v*)&hfL[l15][k0];
#pragma unroll
      for (int r = 0; r < 4; r++) {
        acc[r] = __builtin_amdgcn_mfma_f32_16x16x32_bf16(ah, Wf[r][sl], acc[r], 0, 0, 0);
        acc[r] = __builtin_amdgcn_mfma_f32_16x16x32_bf16(al, Wf[r][sl], acc[r], 0, 0, 0);
      }
    }
#pragma unroll
    for (int r = 0; r < 4; r++) {
      int tile = wid + 8 * r;
      if (tile < 29) {
#pragma unroll
        for (int v = 0; v < 4; v++) gh[kg * 4 + v][tile * 16 + l15] = acc[r][v];
      }
    }
    __syncthreads();
    const int t = tbase + ts;
#pragma unroll
    for (int q = 0; q < 5; q++) if (live[q]) {
      const float* g = (const float*)gh + ghoff[q];
      float ghr = g[0], ghz = g[H], ghn = g[2 * H];
      float r = 1.f / (1.f + __expf(-(xr_[q] + ghr)));
      float z = 1.f / (1.f + __expf(-(xz_[q] + ghz)));
      float ta = fmaf(r, ghn, xn_[q]);
      ta = fminf(fmaxf(ta, -15.f), 15.f);
      float ex = __expf(2.f * ta);
      float n = (ex - 1.f) / (ex + 1.f);
      float hnew = fmaf(z, hq[q] - n, n);
      hq[q] = hnew;
      short hi = f2bf(hnew); float rem = hnew - bf2f(hi);
      ((short*)hfH)[hfoff[q]] = hi; ((short*)hfL)[hfoff[q]] = f2bf(rem);
      int tout = dir ? ((t < Lq[q]) ? (Lq[q] - 1 - t) : t) : t;
      HALL[ho[q] + (size_t)tout * DH] = __float2bfloat16(hnew);
    }
    int tn = (ts + 1 < nsteps) ? ts + 1 : ts;
#pragma unroll
    for (int q = 0; q < 5; q++) {
      const float* p = XP + xpo[q] + (size_t)tn * G3;
      xr_[q] = p[0]; xz_[q] = p[H]; xn_[q] = p[2 * H];
    }
    __syncthreads();
  }
#pragma unroll
  for (int q = 0; q < 5; q++) if (live[q])
    HST[(size_t)(s * B + b0 + (ghoff[q] / 464)) * 152 + (ghoff[q] % 464)] = hq[q];
}

// ---------------- K4: LN-folded MFMA fuse: u=tanh(rs*(h@Wg^T)-rs*mu*sg+cb), E=u@cv^T ----
// grid (1024, 5): x = (b, 32-row t-tile), y = channel
__global__ __launch_bounds__(256) void k_fuse(const __hip_bfloat16* __restrict__ HALL,
    const short* __restrict__ WGH, const short* __restrict__ WGL,
    const float* __restrict__ SG, const float* __restrict__ CB,
    const float* __restrict__ cvw, float* __restrict__ Ebuf) {
  const int mt = blockIdx.x;   // 0..1023
  const int c = blockIdx.y;
  const int b = mt >> 4, ttile = mt & 15;
  const int t0 = ttile << 5;
  const int tid = threadIdx.x, lane = tid & 63, wid = tid >> 6;
  const int l15 = lane & 15, kg = lane >> 4;

  __shared__ short hs[32 * LDA];
  __shared__ short Bh_s[128 * 40];
  __shared__ short Bl_s[128 * 40];
  __shared__ float mu_s[32], rs_s[32];
  __shared__ float U_s[32][132];

  // stage h rows (bf16, exact) padded to KP
  const short* hbase = (const short*)HALL + ((size_t)(c * B + b) * T + t0) * DH;
  for (int f = tid; f < 32 * (KP / 4); f += 256) {
    int r = f / (KP / 4), q = f - r * (KP / 4);
    short4v v{};
    if (q < DH / 4) v = *(const short4v*)(hbase + (size_t)r * DH + q * 4);
    *(short4v*)&hs[r * LDA + q * 4] = v;
  }
  __syncthreads();
  // LN stats per row
  {
    int r = tid >> 3, l8 = tid & 7;
    float sm = 0.f, sq = 0.f;
    for (int e = l8; e < DH; e += 8) {
      float v = bf2f(hs[r * LDA + e]); sm += v; sq += v * v;
    }
    sm += __shfl_xor(sm, 1); sm += __shfl_xor(sm, 2); sm += __shfl_xor(sm, 4);
    sq += __shfl_xor(sq, 1); sq += __shfl_xor(sq, 2); sq += __shfl_xor(sq, 4);
    if (l8 == 0) {
      float mu = sm * (1.f / 300.f);
      float var = fmaxf(sq * (1.f / 300.f) - mu * mu, 0.f);
      mu_s[r] = mu; rs_s[r] = rsqrtf(var + 1e-5f);
    }
  }
  f32x4 acc[2][2] = {};
  for (int sl = 0; sl < 10; sl++) {
    // stage Wg slice: 128 gates x 32 k (hi/lo)
    __syncthreads();
    for (int f = tid; f < 128 * 4; f += 256) {
      int n = f >> 2, q = f & 3;
      size_t go = ((size_t)(c * A + n)) * KP + sl * 32 + q * 8;
      *(short8v*)&Bh_s[n * 40 + q * 8] = *(const short8v*)(WGH + go);
      *(short8v*)&Bl_s[n * 40 + q * 8] = *(const short8v*)(WGL + go);
    }
    __syncthreads();
    short8v ah[2];
#pragma unroll
    for (int m2 = 0; m2 < 2; m2++)
      ah[m2] = *(const short8v*)&hs[(m2 * 16 + l15) * LDA + sl * 32 + kg * 8];
#pragma unroll
    for (int j = 0; j < 2; j++) {
      int n = (2 * wid + j) * 16 + l15;
      short8v bh = *(const short8v*)&Bh_s[n * 40 + kg * 8];
      short8v bl = *(const short8v*)&Bl_s[n * 40 + kg * 8];
#pragma unroll
      for (int m2 = 0; m2 < 2; m2++) {
        acc[m2][j] = __builtin_amdgcn_mfma_f32_16x16x32_bf16(ah[m2], bh, acc[m2][j], 0, 0, 0);
        acc[m2][j] = __builtin_amdgcn_mfma_f32_16x16x32_bf16(ah[m2], bl, acc[m2][j], 0, 0, 0);
      }
    }
  }
  __syncthreads();
#pragma unroll
  for (int j = 0; j < 2; j++) {
    int a = (2 * wid + j) * 16 + l15;
    float sga = SG[c * A + a], cba = CB[c * A + a];
#pragma unroll
    for (int m2 = 0; m2 < 2; m2++) {
#pragma unroll
      for (int v = 0; v < 4; v++) {
        int row = m2 * 16 + kg * 4 + v;
        float val = rs_s[row] * acc[m2][j][v] - mu_s[row] * rs_s[row] * sga + cba;
        U_s[row][a] = tanhf(val);
      }
    }
  }
  __syncthreads();
  const int kc = cKC[c], k0c = cK0[c];
  for (int idx = tid; idx < 32 * kc; idx += 256) {
    int r = idx / kc, kk = idx - r * kc;
    const float* cv = cvw + (size_t)(k0c + kk) * A;
    float e = 0.f;
#pragma unroll 4
    for (int a = 0; a < A; a++) e = fmaf(U_s[r][a], cv[a], e);
    Ebuf[((size_t)(k0c + kk) * B + b) * T + t0 + r] = e;
  }
}

// ---------------- K5: masked softmax over t per (k,b) ----------------
__global__ __launch_bounds__(256) void k_soft(const float* __restrict__ Ebuf,
    const int* __restrict__ Lp, float* __restrict__ ATT) {
  const int k = blockIdx.x >> 6, b = blockIdx.x & 63;
  const int L = Lp[b];
  const float* er = Ebuf + ((size_t)k * B + b) * T;
  float* ar = ATT + ((size_t)k * B + b) * T;
  const int tid = threadIdx.x;
  float v0 = (tid < L) ? er[tid] : -1e30f;
  float v1 = (tid + 256 < L) ? er[tid + 256] : -1e30f;
  float mx = fmaxf(v0, v1);
  __shared__ float red[4];
  __shared__ float red2[4];
#pragma unroll
  for (int off = 32; off; off >>= 1) mx = fmaxf(mx, __shfl_xor(mx, off));
  if ((tid & 63) == 0) red[tid >> 6] = mx;
  __syncthreads();
  mx = fmaxf(fmaxf(red[0], red[1]), fmaxf(red[2], red[3]));
  float e0 = (tid < L) ? expf(v0 - mx) : 0.f;
  float e1 = (tid + 256 < L) ? expf(v1 - mx) : 0.f;
  float sm = e0 + e1;
#pragma unroll
  for (int off = 32; off; off >>= 1) sm += __shfl_xor(sm, off);
  if ((tid & 63) == 0) red2[tid >> 6] = sm;
  __syncthreads();
  sm = red2[0] + red2[1] + red2[2] + red2[3];
  const float inv = 1.f / sm;
  ar[tid] = e0 * inv;
  ar[tid + 256] = e1 * inv;
}

// ---------------- K6: docv[k,b,d] = sum_t att[k,b,t] * h4[b,t,d] ----------------
__global__ __launch_bounds__(256) void k_docv(const __hip_bfloat16* __restrict__ HALL,
    const float* __restrict__ ATT, float* __restrict__ DOCV) {
  const int dt = blockIdx.x, b = blockIdx.y;
  const int d0 = dt << 6;
  const int tid = threadIdx.x, tx = tid & 63, ky = tid >> 6;
  const __hip_bfloat16* hb_ = HALL + ((size_t)(4 * B + b) * T) * DH;
  __shared__ float h_s[64][65];
  __shared__ float att_s[30][66];
  float acc[8] = {};
  const int d = d0 + tx;
  for (int t0 = 0; t0 < T; t0 += 64) {
    for (int f = tid; f < 64 * 64; f += 256) {
      int ttt = f >> 6, dl = f & 63;
      h_s[ttt][dl] = (d0 + dl < DH)
          ? __bfloat162float(hb_[(size_t)(t0 + ttt) * DH + d0 + dl]) : 0.f;
    }
    for (int f = tid; f < 30 * 64; f += 256) {
      int kk = f >> 6, ttt = f & 63;
      att_s[kk][ttt] = ATT[((size_t)kk * B + b) * T + t0 + ttt];
    }
    __syncthreads();
    for (int ttt = 0; ttt < 64; ttt++) {
      float hv = h_s[ttt][tx];
#pragma unroll
      for (int i = 0; i < 8; i++) {
        int kk = ky + (i << 2);
        if (kk < 30) acc[i] = fmaf(att_s[kk][ttt], hv, acc[i]);
      }
    }
    __syncthreads();
  }
  if (d < DH) {
#pragma unroll
    for (int i = 0; i < 8; i++) {
      int kk = ky + (i << 2);
      if (kk < 30) DOCV[((size_t)kk * B + b) * DH + d] = acc[i];
    }
  }
}

// ---------------- K7: group attention + output ----------------
__global__ __launch_bounds__(64) void k_group(const float* __restrict__ DOCV,
    const float* __restrict__ gaw, const float* __restrict__ gab,
    const float* __restrict__ gcv, float* __restrict__ out) {
  const int tt = blockIdx.x / B, b = blockIdx.x % B;
  const int lane = threadIdx.x;
  const int c = cTCAT[tt], cnt = cTC[tt], ks = cTS[tt];
  const float* wrow = gaw + ((size_t)c * 64 + lane) * DH;
  const float gbias = gab[c * 64 + lane];
  const float cvl = gcv[tt * 64 + lane];
  float accd[5] = {0, 0, 0, 0, 0};
  float wsum = 0.f;
  for (int n = 0; n < cnt; n++) {
    const float* drow = DOCV + ((size_t)(ks + n) * B + b) * DH;
    float g = 0.f;
    for (int dd = 0; dd < DH; dd++) g = fmaf(drow[dd], wrow[dd], g);
    g += gbias;
    float p = g * cvl;
#pragma unroll
    for (int off = 32; off; off >>= 1) p += __shfl_xor(p, off);
    float w = expf(tanhf(p));
    wsum += w;
#pragma unroll
    for (int i = 0; i < 5; i++) {
      int dd = lane + (i << 6);
      if (dd < DH) accd[i] = fmaf(w, drow[dd], accd[i]);
    }
  }
  const float inv = 1.f / wsum;
  float* orow = out + ((size_t)tt * B + b) * DH;
#pragma unroll
  for (int i = 0; i < 5; i++) {
    int dd = lane + (i << 6);
    if (dd < DH) orow[dd] = accd[i] * inv;
  }
}

extern "C" void kernel_launch(void* const* d_in, const int* in_sizes, int n_in,
                              void* d_out, int out_size, void* d_ws, size_t ws_size,
                              hipStream_t stream) {
  const float* docs = (const float*)d_in[0];
  const int* lens = (const int*)d_in[1];
  const float* wihf = (const float*)d_in[2];
  const float* whhf = (const float*)d_in[3];
  const float* bihf = (const float*)d_in[4];
  const float* bhhf = (const float*)d_in[5];
  const float* wihb = (const float*)d_in[6];
  const float* whhb = (const float*)d_in[7];
  const float* bihb = (const float*)d_in[8];
  const float* bhhb = (const float*)d_in[9];
  const float* gam = (const float*)d_in[10];
  const float* bet = (const float*)d_in[11];
  const float* saw = (const float*)d_in[12];
  const float* sab = (const float*)d_in[13];
  const float* gaw = (const float*)d_in[14];
  const float* gab = (const float*)d_in[15];
  const float* cvw = (const float*)d_in[16];
  const float* gcv = (const float*)d_in[17];
  float* out = (float*)d_out;

  char* ws = (char*)d_ws;
  size_t off = 0;
  auto alloc = [&](size_t bytes) { size_t o = off; off = (off + bytes + 255) & ~(size_t)255; return o; };
  int* PERM = (int*)(ws + alloc(64 * 4));
  int* LP   = (int*)(ws + alloc(64 * 4));
  __hip_bfloat16* HALL = (__hip_bfloat16*)(ws + alloc((size_t)NC * B * T * DH * 2));
  float* EB   = (float*)(ws + alloc((size_t)NCV * B * T * 4));
  float* ATT  = (float*)(ws + alloc((size_t)NCV * B * T * 4));
  float* DOCV = (float*)(ws + alloc((size_t)NCV * B * DH * 4));
  float* HST  = (float*)(ws + alloc((size_t)640 * 152 * 4));
  short* WGH  = (short*)(ws + alloc((size_t)NC * A * KP * 2));
  short* WGL  = (short*)(ws + alloc((size_t)NC * A * KP * 2));
  float* SG   = (float*)(ws + alloc((size_t)NC * A * 4));
  float* CB   = (float*)(ws + alloc((size_t)NC * A * 4));
  short* DXH  = (short*)(ws + alloc((size_t)B * T * KP * 2));
  short* DXL  = (short*)(ws + alloc((size_t)B * T * KP * 2));
  size_t fixed = off;

  int chunkT = 64;
  for (int cT = 512; cT >= 64; cT >>= 1) {
    size_t xpb = (size_t)10 * B * cT * G3 * 4;
    if (fixed + xpb <= ws_size) { chunkT = cT; break; }
  }
  float* XP = (float*)(ws + fixed);
  const int nMt = chunkT >> 5;

  hipLaunchKernelGGL(k_perm, dim3(1), dim3(64), 0, stream, lens, PERM, LP);
  hipLaunchKernelGGL(k_prepx, dim3(2048), dim3(256), 0, stream, docs, DXH, DXL);
  hipLaunchKernelGGL(k_prepw, dim3(NC * A), dim3(64), 0, stream,
                     saw, sab, gam, bet, WGH, WGL, SG, CB);
  for (int tbase = 0; tbase < T; tbase += chunkT) {
    hipLaunchKernelGGL(k_xp, dim3(80, (B * chunkT / 32) / 8), dim3(256), 0, stream,
                       DXH, DXL, wihf, wihb, bihf, bihb, PERM, LP, XP, tbase, nMt, chunkT);
    hipLaunchKernelGGL(k_gru, dim3(40), dim3(512), 0, stream,
                       whhf, whhb, bhhf, bhhb, LP, XP, HALL, HST, tbase, chunkT, chunkT);
  }
  hipLaunchKernelGGL(k_fuse, dim3(1024, 5), dim3(256), 0, stream,
                     HALL, WGH, WGL, SG, CB, cvw, EB);
  hipLaunchKernelGGL(k_soft, dim3(1920), dim3(256), 0, stream, EB, LP, ATT);
  hipLaunchKernelGGL(k_docv, dim3(5, 64), dim3(256), 0, stream, HALL, ATT, DOCV);
  hipLaunchKernelGGL(k_group, dim3(576), dim3(64), 0, stream, DOCV, gaw, gab, gcv, out);
}

// Round 5
// 2148.961 us; speedup vs baseline: 3.4001x; 1.0851x over previous
//
#include <hip/hip_runtime.h>
#include <hip/hip_bf16.h>
#include <math.h>

#define B   64
#define T   512
#define E   300
#define H   150
#define G3  450   // 3*H
#define DH  300   // 2*H
#define A   128
#define NC  5
#define NCV 30
#define KP  320   // padded K (E and DH both <= 320, 10 slices of 32)
#define LDA 328   // LDS row stride in shorts
#define CHK 64    // T-chunk for the fused xp/gru pipeline

__constant__ int cK0[NC]  = {0,9,12,18,24};
__constant__ int cKC[NC]  = {9,3,6,6,6};
__constant__ int cTS[9]   = {0,3,6,9,12,18,21,24,27};
__constant__ int cTC[9]   = {3,3,3,3,6,3,3,3,3};
__constant__ int cTCAT[9] = {0,0,0,1,2,3,3,4,4};

typedef __attribute__((ext_vector_type(8))) short short8v;
typedef __attribute__((ext_vector_type(4))) short short4v;
typedef __attribute__((ext_vector_type(4))) float f32x4;

__device__ __forceinline__ short f2bf(float v) {
  unsigned u = __builtin_bit_cast(unsigned, v);
  u += 0x7FFFu + ((u >> 16) & 1u);
  return (short)(u >> 16);
}
__device__ __forceinline__ float bf2f(short s) {
  unsigned u = ((unsigned)(unsigned short)s) << 16;
  return __builtin_bit_cast(float, u);
}
// barrier that does NOT drain vmcnt (global loads stay in flight).
// LDS producer->consumer only needs lgkmcnt. sched_barrier pins ordering (rule #18).
__device__ __forceinline__ void bar_lgkm() {
  asm volatile("s_waitcnt lgkmcnt(0)" ::: "memory");
  __builtin_amdgcn_s_barrier();
  __builtin_amdgcn_sched_barrier(0);
}
__device__ __forceinline__ float fast_sig(float x) {
  return __builtin_amdgcn_rcpf(1.f + __expf(-x));
}
__device__ __forceinline__ float fast_tanh(float x) {
  x = fminf(fmaxf(x, -15.f), 15.f);
  float ex = __expf(2.f * x);
  return (ex - 1.f) * __builtin_amdgcn_rcpf(ex + 1.f);
}

// ---------------- K1: stable argsort(-lengths) ----------------
__global__ void k_perm(const int* __restrict__ len, int* __restrict__ perm,
                       int* __restrict__ Lp) {
  __shared__ int sp[B];
  int b = threadIdx.x;
  int lb = len[b];
  int rank = 0;
  for (int j = 0; j < B; j++) {
    int lj = len[j];
    rank += (lj > lb) || (lj == lb && j < b);
  }
  sp[rank] = b;
  __syncthreads();
  perm[b] = sp[b];
  Lp[b] = len[sp[b]];
}

// ---------------- prep: docs -> bf16 hi/lo, padded to KP ----------------
__global__ __launch_bounds__(256) void k_prepx(const float* __restrict__ docs,
    short* __restrict__ DXH, short* __restrict__ DXL) {
  const int total = B * T * (KP / 8);
  for (int i = blockIdx.x * 256 + threadIdx.x; i < total; i += gridDim.x * 256) {
    int bt = i / (KP / 8), q = i - bt * (KP / 8);
    const float* src = docs + (size_t)bt * E + q * 8;
    short8v h{}, l{};
#pragma unroll
    for (int j = 0; j < 8; j++) {
      int e = q * 8 + j;
      float v = (e < E) ? src[j] : 0.f;
      short hi = f2bf(v);
      h[j] = hi; l[j] = f2bf(v - bf2f(hi));
    }
    *(short8v*)(DXH + (size_t)bt * KP + q * 8) = h;
    *(short8v*)(DXL + (size_t)bt * KP + q * 8) = l;
  }
}

// ---------------- prep: Wg = gamma * sent_att_w (hi/lo), sg, cb ----------------
__global__ __launch_bounds__(64) void k_prepw(const float* __restrict__ saw,
    const float* __restrict__ sab, const float* __restrict__ gamma,
    const float* __restrict__ beta, short* __restrict__ WGH,
    short* __restrict__ WGL, float* __restrict__ SG, float* __restrict__ CB) {
  const int blk = blockIdx.x;          // c*128 + a
  const int c = blk >> 7;
  const int lane = threadIdx.x;
  const float* wrow = saw + (size_t)blk * DH;
  float sg = 0.f, cbv = 0.f;
  for (int e = lane; e < KP; e += 64) {
    float wg = 0.f;
    if (e < DH) {
      float w = wrow[e];
      wg = w * gamma[c * DH + e];
      sg += wg;
      cbv += beta[c * DH + e] * w;
    }
    short hi = f2bf(wg);
    WGH[(size_t)blk * KP + e] = hi;
    WGL[(size_t)blk * KP + e] = f2bf(wg - bf2f(hi));
  }
#pragma unroll
  for (int off = 32; off; off >>= 1) { sg += __shfl_xor(sg, off); cbv += __shfl_xor(cbv, off); }
  if (lane == 0) { SG[blk] = sg; CB[blk] = cbv + sab[blk]; }
}

// ================= fused XP+GRU kernel =================
// mode 0: blocks [0,40) = GRU(gtbase, XPg); blocks [40,680) = XP(xtbase -> XPx)
// mode 1: all blocks XP ; mode 2: all blocks GRU
__global__ __launch_bounds__(512, 1) void k_xg(int mode, int gtbase, int xtbase,
    const float* __restrict__ XPg, float* __restrict__ XPx,
    const short* __restrict__ DXH, const short* __restrict__ DXL,
    const float* __restrict__ wihf, const float* __restrict__ wihb,
    const float* __restrict__ bihf, const float* __restrict__ bihb,
    const float* __restrict__ whf, const float* __restrict__ whb,
    const float* __restrict__ bhf, const float* __restrict__ bhb,
    const int* __restrict__ perm, const int* __restrict__ Lp,
    __hip_bfloat16* __restrict__ HALL, float* __restrict__ HST) {
  extern __shared__ __align__(16) char smem[];
  const int tid = threadIdx.x, lane = tid & 63, wid = tid >> 6;
  const int l15 = lane & 15, kg = lane >> 4;
  bool isGru; int xpBlk;
  if (mode == 0) { isGru = (int)blockIdx.x < 40; xpBlk = blockIdx.x - 40; }
  else if (mode == 1) { isGru = false; xpBlk = blockIdx.x; }
  else { isGru = true; xpBlk = 0; }

  if (!isGru) {
    // ---------------- XP body: 128 gates x 32 rows per iter, 8 iters ----------------
    const int y = xpBlk / 40, sn = xpBlk - y * 40;
    const int s = sn >> 2, nt = sn & 3;
    const int c = s >> 1, dir = s & 1;
    const float* W  = (dir ? wihb : wihf) + (size_t)c * G3 * E;
    const float* Bi = (dir ? bihb : bihf) + (size_t)c * G3;
    const int gw = nt * 128 + wid * 16 + l15;
    const bool gv = gw < G3;
    const float biasv = gv ? Bi[gw] : 0.f;
    short8v Whi[10], Wlo[10];
#pragma unroll
    for (int sl = 0; sl < 10; sl++) {
      short8v hi{}, lo{};
      if (gv) {
#pragma unroll
        for (int j = 0; j < 8; j++) {
          int k = sl * 32 + kg * 8 + j;
          if (k < E) {
            float w = W[(size_t)gw * E + k];
            short h = f2bf(w);
            hi[j] = h; lo[j] = f2bf(w - bf2f(h));
          }
        }
      }
      Whi[sl] = hi; Wlo[sl] = lo;
    }
    short* Ah = (short*)smem;            // 32*LDA
    short* Al = (short*)(smem + 32 * LDA * 2);
    for (int i = 0; i < 8; i++) {
      const int idx = y * 8 + i;           // 0..127
      const int b = idx >> 1, mtile = idx & 1;
      const int L = Lp[b];
      const int pb = perm[b];
      const int t0g = xtbase + mtile * 32;
      for (int f = tid; f < 32 * (KP / 8); f += 512) {
        int r = f / (KP / 8), q = f - r * (KP / 8);
        int tg = t0g + r;
        int src = (dir && tg < L) ? (L - 1 - tg) : tg;
        size_t go = ((size_t)pb * T + src) * KP + q * 8;
        *(short8v*)&Ah[r * LDA + q * 8] = *(const short8v*)(DXH + go);
        *(short8v*)&Al[r * LDA + q * 8] = *(const short8v*)(DXL + go);
      }
      __syncthreads();
      f32x4 acc[2];
#pragma unroll
      for (int m2 = 0; m2 < 2; m2++) acc[m2] = f32x4{biasv, biasv, biasv, biasv};
#pragma unroll
      for (int sl = 0; sl < 10; sl++) {
#pragma unroll
        for (int m2 = 0; m2 < 2; m2++) {
          const int ro = (m2 * 16 + l15) * LDA + sl * 32 + kg * 8;
          short8v ah = *(const short8v*)&Ah[ro];
          short8v al = *(const short8v*)&Al[ro];
          acc[m2] = __builtin_amdgcn_mfma_f32_16x16x32_bf16(ah, Whi[sl], acc[m2], 0, 0, 0);
          acc[m2] = __builtin_amdgcn_mfma_f32_16x16x32_bf16(ah, Wlo[sl], acc[m2], 0, 0, 0);
          acc[m2] = __builtin_amdgcn_mfma_f32_16x16x32_bf16(al, Whi[sl], acc[m2], 0, 0, 0);
        }
      }
      if (gv) {
        const size_t base = (size_t)(s * B + b) * CHK * G3;
#pragma unroll
        for (int m2 = 0; m2 < 2; m2++) {
          const int lt = mtile * 32 + m2 * 16 + kg * 4;
          float* xp = XPx + base + (size_t)lt * G3 + gw;
#pragma unroll
          for (int v = 0; v < 4; v++) xp[(size_t)v * G3] = acc[m2][v];
        }
      }
      __syncthreads();
    }
    return;
  }

  // ---------------- GRU body: 16 batches, raw lgkm barriers ----------------
  const int blk = blockIdx.x;         // 0..39
  const int s = blk >> 2, bt = blk & 3;
  const int b0 = bt << 4;
  const int c = s >> 1, dir = s & 1;
  const float* Whh = (dir ? whb : whf) + (size_t)c * G3 * H;
  const float* Bhh = (dir ? bhb : bhf) + (size_t)c * G3;
  float (*gh)[464]  = (float(*)[464])smem;              // 29696 B
  short (*hfH)[168] = (short(*)[168])(smem + 29696);    // 5376 B
  short (*hfL)[168] = (short(*)[168])(smem + 29696 + 5376);

  short8v Wf[4][5];
  float bias[4];
#pragma unroll
  for (int r = 0; r < 4; r++) {
    int tile = wid + 8 * r;
    int gate = tile * 16 + l15;
    bool gvv = (tile < 29) && (gate < G3);
    bias[r] = gvv ? Bhh[gate] : 0.f;
#pragma unroll
    for (int sl = 0; sl < 5; sl++) {
      short8v w = {};
      if (gvv) {
        int k0 = sl * 32 + kg * 8;
#pragma unroll
        for (int j = 0; j < 8; j++) {
          int k = k0 + j;
          if (k < H) w[j] = f2bf(Whh[(size_t)gate * H + k]);
        }
      }
      Wf[r][sl] = w;
    }
  }

  bool live[5]; float hq[5]; int Lq[5], ghoff[5], hfoff[5];
  size_t xpo[5], ho[5];
#pragma unroll
  for (int q = 0; q < 5; q++) {
    int i = tid + 512 * q;
    live[q] = (i < 2400);
    int bl = live[q] ? (i / 150) : 0;
    int j  = live[q] ? (i - bl * 150) : 0;
    int bg = b0 + bl;
    Lq[q] = Lp[bg];
    ghoff[q] = bl * 464 + j;
    hfoff[q] = bl * 168 + j;
    xpo[q] = ((size_t)(s * B + bg) * CHK) * G3 + j;
    ho[q]  = ((size_t)(c * B + bg) * T) * DH + (size_t)dir * H + j;
    hq[q] = 0.f;
    if (gtbase > 0 && live[q]) hq[q] = HST[(size_t)(s * B + bg) * 152 + j];
  }

  for (int f = tid; f < 16 * 168; f += 512) {
    int kk = f % 168;
    if (kk >= H) { ((short*)hfH)[f] = 0; ((short*)hfL)[f] = 0; }
  }
#pragma unroll
  for (int q = 0; q < 5; q++) if (live[q]) {
    short hi = f2bf(hq[q]); float rem = hq[q] - bf2f(hi);
    ((short*)hfH)[hfoff[q]] = hi; ((short*)hfL)[hfoff[q]] = f2bf(rem);
  }
  float xr_[5], xz_[5], xn_[5];
#pragma unroll
  for (int q = 0; q < 5; q++) {
    const float* p = XPg + xpo[q];
    xr_[q] = p[0]; xz_[q] = p[H]; xn_[q] = p[2 * H];
  }
  __syncthreads();

  for (int ts = 0; ts < CHK; ts++) {
    f32x4 acc[4];
#pragma unroll
    for (int r = 0; r < 4; r++) acc[r] = f32x4{bias[r], bias[r], bias[r], bias[r]};
#pragma unroll
    for (int sl = 0; sl < 5; sl++) {
      int k0 = sl * 32 + kg * 8;
      short8v ah = *(const short8v*)&hfH[l15][k0];
      short8v al = *(const short8v*)&hfL[l15][k0];
#pragma unroll
      for (int r = 0; r < 4; r++) {
        acc[r] = __builtin_amdgcn_mfma_f32_16x16x32_bf16(ah, Wf[r][sl], acc[r], 0, 0, 0);
        acc[r] = __builtin_amdgcn_mfma_f32_16x16x32_bf16(al, Wf[r][sl], acc[r], 0, 0, 0);
      }
    }
#pragma unroll
    for (int r = 0; r < 4; r++) {
      int tile = wid + 8 * r;
      if (tile < 29) {
#pragma unroll
        for (int v = 0; v < 4; v++) gh[kg * 4 + v][tile * 16 + l15] = acc[r][v];
      }
    }
    bar_lgkm();
    const int t = gtbase + ts;
#pragma unroll
    for (int q = 0; q < 5; q++) if (live[q]) {
      const float* g = (const float*)gh + ghoff[q];
      float ghr = g[0], ghz = g[H], ghn = g[2 * H];
      float r = fast_sig(xr_[q] + ghr);
      float z = fast_sig(xz_[q] + ghz);
      float n = fast_tanh(fmaf(r, ghn, xn_[q]));
      float hnew = fmaf(z, hq[q] - n, n);
      hq[q] = hnew;
      short hi = f2bf(hnew); float rem = hnew - bf2f(hi);
      ((short*)hfH)[hfoff[q]] = hi; ((short*)hfL)[hfoff[q]] = f2bf(rem);
      int tout = dir ? ((t < Lq[q]) ? (Lq[q] - 1 - t) : t) : t;
      HALL[ho[q] + (size_t)tout * DH] = __float2bfloat16(hnew);
    }
    int tn = (ts + 1 < CHK) ? ts + 1 : ts;
#pragma unroll
    for (int q = 0; q < 5; q++) {
      const float* p = XPg + xpo[q] + (size_t)tn * G3;
      xr_[q] = p[0]; xz_[q] = p[H]; xn_[q] = p[2 * H];
    }
    bar_lgkm();
  }
#pragma unroll
  for (int q = 0; q < 5; q++) if (live[q])
    HST[(size_t)(s * B + b0 + (ghoff[q] / 464)) * 152 + (ghoff[q] % 464)] = hq[q];
}

// ---------------- K4: LN-folded MFMA fuse, W persistent in regs ----------------
// grid (128, 5): x = b*2 + half(8 t-tiles), y = channel
__global__ __launch_bounds__(256) void k_fuse(const __hip_bfloat16* __restrict__ HALL,
    const short* __restrict__ WGH, const short* __restrict__ WGL,
    const float* __restrict__ SG, const float* __restrict__ CB,
    const float* __restrict__ cvw, float* __restrict__ Ebuf) {
  const int c = blockIdx.y;
  const int b = blockIdx.x >> 1, half = blockIdx.x & 1;
  const int tid = threadIdx.x, lane = tid & 63, wid = tid >> 6;
  const int l15 = lane & 15, kg = lane >> 4;
  __shared__ short hs[32 * LDA];
  __shared__ float mu_s[32], rs_s[32];
  __shared__ float U_s[32][132];

  // persistent Wg fragments: 2 n-tiles/wave x 10 slices, hi/lo
  short8v Wh[2][10], Wl[2][10];
  float sga[2], cba[2];
#pragma unroll
  for (int j = 0; j < 2; j++) {
    int n = (wid * 2 + j) * 16 + l15;
    sga[j] = SG[c * A + n]; cba[j] = CB[c * A + n];
#pragma unroll
    for (int sl = 0; sl < 10; sl++) {
      size_t go = ((size_t)(c * A + n)) * KP + sl * 32 + kg * 8;
      Wh[j][sl] = *(const short8v*)(WGH + go);
      Wl[j][sl] = *(const short8v*)(WGL + go);
    }
  }
  const int kc = cKC[c], k0c = cK0[c];
  for (int tt = 0; tt < 8; tt++) {
    const int t0 = (half * 8 + tt) * 32;
    const short* hbase = (const short*)HALL + ((size_t)(c * B + b) * T + t0) * DH;
    for (int f = tid; f < 32 * 80; f += 256) {
      int r = f / 80, g4 = f - r * 80;
      short4v v{};
      if (g4 < 75) v = *(const short4v*)(hbase + (size_t)r * DH + g4 * 4);
      *(short4v*)&hs[r * LDA + g4 * 4] = v;
    }
    __syncthreads();
    {
      int r = tid >> 3, l8 = tid & 7;
      float sm = 0.f, sq = 0.f;
      for (int e = l8; e < DH; e += 8) {
        float v = bf2f(hs[r * LDA + e]); sm += v; sq += v * v;
      }
      sm += __shfl_xor(sm, 1); sm += __shfl_xor(sm, 2); sm += __shfl_xor(sm, 4);
      sq += __shfl_xor(sq, 1); sq += __shfl_xor(sq, 2); sq += __shfl_xor(sq, 4);
      if (l8 == 0) {
        float mu = sm * (1.f / 300.f);
        float var = fmaxf(sq * (1.f / 300.f) - mu * mu, 0.f);
        mu_s[r] = mu; rs_s[r] = rsqrtf(var + 1e-5f);
      }
    }
    __syncthreads();
    f32x4 acc[2][2] = {};
#pragma unroll
    for (int sl = 0; sl < 10; sl++) {
      short8v ah[2];
#pragma unroll
      for (int m2 = 0; m2 < 2; m2++)
        ah[m2] = *(const short8v*)&hs[(m2 * 16 + l15) * LDA + sl * 32 + kg * 8];
#pragma unroll
      for (int j = 0; j < 2; j++) {
#pragma unroll
        for (int m2 = 0; m2 < 2; m2++) {
          acc[m2][j] = __builtin_amdgcn_mfma_f32_16x16x32_bf16(ah[m2], Wh[j][sl], acc[m2][j], 0, 0, 0);
          acc[m2][j] = __builtin_amdgcn_mfma_f32_16x16x32_bf16(ah[m2], Wl[j][sl], acc[m2][j], 0, 0, 0);
        }
      }
    }
#pragma unroll
    for (int j = 0; j < 2; j++) {
      int a = (wid * 2 + j) * 16 + l15;
#pragma unroll
      for (int m2 = 0; m2 < 2; m2++) {
#pragma unroll
        for (int v = 0; v < 4; v++) {
          int row = m2 * 16 + kg * 4 + v;
          float val = rs_s[row] * acc[m2][j][v] - mu_s[row] * rs_s[row] * sga[j] + cba[j];
          U_s[row][a] = fast_tanh(val);
        }
      }
    }
    __syncthreads();
    for (int idx = tid; idx < 32 * kc; idx += 256) {
      int r = idx / kc, kk = idx - r * kc;
      const float* cv = cvw + (size_t)(k0c + kk) * A;
      float e = 0.f;
#pragma unroll 4
      for (int a = 0; a < A; a++) e = fmaf(U_s[r][a], cv[a], e);
      Ebuf[((size_t)(k0c + kk) * B + b) * T + t0 + r] = e;
    }
    __syncthreads();
  }
}

// ---------------- K5: masked softmax over t per (k,b), in-place ----------------
__global__ __launch_bounds__(256) void k_soft(float* __restrict__ Ebuf,
    const int* __restrict__ Lp) {
  const int k = blockIdx.x >> 6, b = blockIdx.x & 63;
  const int L = Lp[b];
  float* er = Ebuf + ((size_t)k * B + b) * T;
  const int tid = threadIdx.x;
  float v0 = (tid < L) ? er[tid] : -1e30f;
  float v1 = (tid + 256 < L) ? er[tid + 256] : -1e30f;
  float mx = fmaxf(v0, v1);
  __shared__ float red[4];
  __shared__ float red2[4];
#pragma unroll
  for (int off = 32; off; off >>= 1) mx = fmaxf(mx, __shfl_xor(mx, off));
  if ((tid & 63) == 0) red[tid >> 6] = mx;
  __syncthreads();
  mx = fmaxf(fmaxf(red[0], red[1]), fmaxf(red[2], red[3]));
  float e0 = (tid < L) ? __expf(v0 - mx) : 0.f;
  float e1 = (tid + 256 < L) ? __expf(v1 - mx) : 0.f;
  float sm = e0 + e1;
#pragma unroll
  for (int off = 32; off; off >>= 1) sm += __shfl_xor(sm, off);
  if ((tid & 63) == 0) red2[tid >> 6] = sm;
  __syncthreads();
  sm = red2[0] + red2[1] + red2[2] + red2[3];
  const float inv = 1.f / sm;
  er[tid] = e0 * inv;
  er[tid + 256] = e1 * inv;
}

// ---------------- K6: docv[k,b,d] = sum_t att[k,b,t] * h4[b,t,d] ----------------
__global__ __launch_bounds__(256) void k_docv(const __hip_bfloat16* __restrict__ HALL,
    const float* __restrict__ ATT, float* __restrict__ DOCV) {
  const int dt = blockIdx.x, b = blockIdx.y;
  const int d0 = dt << 6;
  const int tid = threadIdx.x, tx = tid & 63, ky = tid >> 6;
  const __hip_bfloat16* hb_ = HALL + ((size_t)(4 * B + b) * T) * DH;
  __shared__ float h_s[64][65];
  __shared__ float att_s[30][66];
  float acc[8] = {};
  const int d = d0 + tx;
  for (int t0 = 0; t0 < T; t0 += 64) {
    for (int f = tid; f < 64 * 64; f += 256) {
      int ttt = f >> 6, dl = f & 63;
      h_s[ttt][dl] = (d0 + dl < DH)
          ? __bfloat162float(hb_[(size_t)(t0 + ttt) * DH + d0 + dl]) : 0.f;
    }
    for (int f = tid; f < 30 * 64; f += 256) {
      int kk = f >> 6, ttt = f & 63;
      att_s[kk][ttt] = ATT[((size_t)kk * B + b) * T + t0 + ttt];
    }
    __syncthreads();
    for (int ttt = 0; ttt < 64; ttt++) {
      float hv = h_s[ttt][tx];
#pragma unroll
      for (int i = 0; i < 8; i++) {
        int kk = ky + (i << 2);
        if (kk < 30) acc[i] = fmaf(att_s[kk][ttt], hv, acc[i]);
      }
    }
    __syncthreads();
  }
  if (d < DH) {
#pragma unroll
    for (int i = 0; i < 8; i++) {
      int kk = ky + (i << 2);
      if (kk < 30) DOCV[((size_t)kk * B + b) * DH + d] = acc[i];
    }
  }
}

// ---------------- K7: group attention + output ----------------
__global__ __launch_bounds__(64) void k_group(const float* __restrict__ DOCV,
    const float* __restrict__ gaw, const float* __restrict__ gab,
    const float* __restrict__ gcv, float* __restrict__ out) {
  const int tt = blockIdx.x / B, b = blockIdx.x % B;
  const int lane = threadIdx.x;
  const int c = cTCAT[tt], cnt = cTC[tt], ks = cTS[tt];
  const float* wrow = gaw + ((size_t)c * 64 + lane) * DH;
  const float gbias = gab[c * 64 + lane];
  const float cvl = gcv[tt * 64 + lane];
  float accd[5] = {0, 0, 0, 0, 0};
  float wsum = 0.f;
  for (int n = 0; n < cnt; n++) {
    const float* drow = DOCV + ((size_t)(ks + n) * B + b) * DH;
    float g = 0.f;
    for (int dd = 0; dd < DH; dd++) g = fmaf(drow[dd], wrow[dd], g);
    g += gbias;
    float p = g * cvl;
#pragma unroll
    for (int off = 32; off; off >>= 1) p += __shfl_xor(p, off);
    float w = __expf(tanhf(p));
    wsum += w;
#pragma unroll
    for (int i = 0; i < 5; i++) {
      int dd = lane + (i << 6);
      if (dd < DH) accd[i] = fmaf(w, drow[dd], accd[i]);
    }
  }
  const float inv = 1.f / wsum;
  float* orow = out + ((size_t)tt * B + b) * DH;
#pragma unroll
  for (int i = 0; i < 5; i++) {
    int dd = lane + (i << 6);
    if (dd < DH) orow[dd] = accd[i] * inv;
  }
}

extern "C" void kernel_launch(void* const* d_in, const int* in_sizes, int n_in,
                              void* d_out, int out_size, void* d_ws, size_t ws_size,
                              hipStream_t stream) {
  const float* docs = (const float*)d_in[0];
  const int* lens = (const int*)d_in[1];
  const float* wihf = (const float*)d_in[2];
  const float* whhf = (const float*)d_in[3];
  const float* bihf = (const float*)d_in[4];
  const float* bhhf = (const float*)d_in[5];
  const float* wihb = (const float*)d_in[6];
  const float* whhb = (const float*)d_in[7];
  const float* bihb = (const float*)d_in[8];
  const float* bhhb = (const float*)d_in[9];
  const float* gam = (const float*)d_in[10];
  const float* bet = (const float*)d_in[11];
  const float* saw = (const float*)d_in[12];
  const float* sab = (const float*)d_in[13];
  const float* gaw = (const float*)d_in[14];
  const float* gab = (const float*)d_in[15];
  const float* cvw = (const float*)d_in[16];
  const float* gcv = (const float*)d_in[17];
  float* out = (float*)d_out;

  char* ws = (char*)d_ws;
  size_t off = 0;
  auto alloc = [&](size_t bytes) { size_t o = off; off = (off + bytes + 255) & ~(size_t)255; return o; };
  int* PERM = (int*)(ws + alloc(64 * 4));
  int* LP   = (int*)(ws + alloc(64 * 4));
  __hip_bfloat16* HALL = (__hip_bfloat16*)(ws + alloc((size_t)NC * B * T * DH * 2));
  float* EB   = (float*)(ws + alloc((size_t)NCV * B * T * 4));
  float* DOCV = (float*)(ws + alloc((size_t)NCV * B * DH * 4));
  float* HST  = (float*)(ws + alloc((size_t)640 * 152 * 4));
  short* WGH  = (short*)(ws + alloc((size_t)NC * A * KP * 2));
  short* WGL  = (short*)(ws + alloc((size_t)NC * A * KP * 2));
  float* SG   = (float*)(ws + alloc((size_t)NC * A * 4));
  float* CB   = (float*)(ws + alloc((size_t)NC * A * 4));
  short* DXH  = (short*)(ws + alloc((size_t)B * T * KP * 2));
  short* DXL  = (short*)(ws + alloc((size_t)B * T * KP * 2));
  const size_t xpBytes = (size_t)10 * B * CHK * G3 * 4;   // 73.7 MB
  const bool dbuf = (off + 2 * xpBytes + 512) <= ws_size;
  float* XP0 = (float*)(ws + alloc(xpBytes));
  float* XP1 = dbuf ? (float*)(ws + alloc(xpBytes)) : XP0;

  const int DYN = 32 * LDA * 2 * 2;   // 41984 B (xp >= gru's 40448)
  const int NXP = 640;                // 16 y-tiles * 40 (s,nt)

  hipLaunchKernelGGL(k_perm, dim3(1), dim3(64), 0, stream, lens, PERM, LP);
  hipLaunchKernelGGL(k_prepx, dim3(2048), dim3(256), 0, stream, docs, DXH, DXL);
  hipLaunchKernelGGL(k_prepw, dim3(NC * A), dim3(64), 0, stream,
                     saw, sab, gam, bet, WGH, WGL, SG, CB);
  if (dbuf) {
    // prologue: XP chunk 0 -> XP0
    hipLaunchKernelGGL(k_xg, dim3(NXP), dim3(512), DYN, stream, 1, 0, 0,
                       XP0, XP0, DXH, DXL, wihf, wihb, bihf, bihb,
                       whhf, whhb, bhhf, bhhb, PERM, LP, HALL, HST);
    for (int j = 0; j < 7; j++) {
      float* g = (j & 1) ? XP1 : XP0;
      float* x = (j & 1) ? XP0 : XP1;
      hipLaunchKernelGGL(k_xg, dim3(40 + NXP), dim3(512), DYN, stream, 0,
                         j * CHK, (j + 1) * CHK, g, x, DXH, DXL,
                         wihf, wihb, bihf, bihb, whhf, whhb, bhhf, bhhb,
                         PERM, LP, HALL, HST);
    }
    hipLaunchKernelGGL(k_xg, dim3(40), dim3(512), DYN, stream, 2,
                       7 * CHK, 0, XP1, XP1, DXH, DXL,
                       wihf, wihb, bihf, bihb, whhf, whhb, bhhf, bhhb,
                       PERM, LP, HALL, HST);
  } else {
    for (int j = 0; j < 8; j++) {
      hipLaunchKernelGGL(k_xg, dim3(NXP), dim3(512), DYN, stream, 1,
                         0, j * CHK, XP0, XP0, DXH, DXL,
                         wihf, wihb, bihf, bihb, whhf, whhb, bhhf, bhhb,
                         PERM, LP, HALL, HST);
      hipLaunchKernelGGL(k_xg, dim3(40), dim3(512), DYN, stream, 2,
                         j * CHK, 0, XP0, XP0, DXH, DXL,
                         wihf, wihb, bihf, bihb, whhf, whhb, bhhf, bhhb,
                         PERM, LP, HALL, HST);
    }
  }
  hipLaunchKernelGGL(k_fuse, dim3(128, 5), dim3(256), 0, stream,
                     HALL, WGH, WGL, SG, CB, cvw, EB);
  hipLaunchKernelGGL(k_soft, dim3(1920), dim3(256), 0, stream, EB, LP);
  hipLaunchKernelGGL(k_docv, dim3(5, 64), dim3(256), 0, stream, HALL, EB, DOCV);
  hipLaunchKernelGGL(k_group, dim3(576), dim3(64), 0, stream, DOCV, gaw, gab, gcv, out);
}

// Round 6
// 1823.648 us; speedup vs baseline: 4.0066x; 1.1784x over previous
//
#include <hip/hip_runtime.h>
#include <hip/hip_bf16.h>
#include <math.h>

#define B   64
#define T   512
#define E   300
#define H   150
#define G3  450   // 3*H
#define DH  300   // 2*H
#define A   128
#define NC  5
#define NCV 30
#define KP  320   // padded K for E/DH (10 slices of 32)
#define G3P 480   // permuted/padded gate dim: 3 sections of 160
#define LDA 328   // LDS row stride in shorts
#define CHK 64    // T-chunk for the fused xp/gru pipeline

__constant__ int cK0[NC]  = {0,9,12,18,24};
__constant__ int cKC[NC]  = {9,3,6,6,6};
__constant__ int cTS[9]   = {0,3,6,9,12,18,21,24,27};
__constant__ int cTC[9]   = {3,3,3,3,6,3,3,3,3};
__constant__ int cTCAT[9] = {0,0,0,1,2,3,3,4,4};

typedef __attribute__((ext_vector_type(8))) short short8v;
typedef __attribute__((ext_vector_type(4))) short short4v;
typedef __attribute__((ext_vector_type(4))) float f32x4;

__device__ __forceinline__ short f2bf(float v) {
  unsigned u = __builtin_bit_cast(unsigned, v);
  u += 0x7FFFu + ((u >> 16) & 1u);
  return (short)(u >> 16);
}
__device__ __forceinline__ float bf2f(short s) {
  unsigned u = ((unsigned)(unsigned short)s) << 16;
  return __builtin_bit_cast(float, u);
}
// barrier that does NOT drain vmcnt; LDS producer->consumer needs lgkm only.
__device__ __forceinline__ void bar_lgkm() {
  asm volatile("s_waitcnt lgkmcnt(0)" ::: "memory");
  __builtin_amdgcn_s_barrier();
  __builtin_amdgcn_sched_barrier(0);
}
__device__ __forceinline__ float fast_sig(float x) {
  return __builtin_amdgcn_rcpf(1.f + __expf(-x));
}
__device__ __forceinline__ float fast_tanh(float x) {
  x = fminf(fmaxf(x, -15.f), 15.f);
  float ex = __expf(2.f * x);
  return (ex - 1.f) * __builtin_amdgcn_rcpf(ex + 1.f);
}

// ---------------- K1: stable argsort(-lengths) ----------------
__global__ void k_perm(const int* __restrict__ len, int* __restrict__ perm,
                       int* __restrict__ Lp) {
  __shared__ int sp[B];
  int b = threadIdx.x;
  int lb = len[b];
  int rank = 0;
  for (int j = 0; j < B; j++) {
    int lj = len[j];
    rank += (lj > lb) || (lj == lb && j < b);
  }
  sp[rank] = b;
  __syncthreads();
  perm[b] = sp[b];
  Lp[b] = len[sp[b]];
}

// ---------------- prep: docs -> bf16 hi/lo, padded to KP ----------------
__global__ __launch_bounds__(256) void k_prepx(const float* __restrict__ docs,
    short* __restrict__ DXH, short* __restrict__ DXL) {
  const int total = B * T * (KP / 8);
  for (int i = blockIdx.x * 256 + threadIdx.x; i < total; i += gridDim.x * 256) {
    int bt = i / (KP / 8), q = i - bt * (KP / 8);
    const float* src = docs + (size_t)bt * E + q * 8;
    short8v h{}, l{};
#pragma unroll
    for (int j = 0; j < 8; j++) {
      int e = q * 8 + j;
      float v = (e < E) ? src[j] : 0.f;
      short hi = f2bf(v);
      h[j] = hi; l[j] = f2bf(v - bf2f(hi));
    }
    *(short8v*)(DXH + (size_t)bt * KP + q * 8) = h;
    *(short8v*)(DXL + (size_t)bt * KP + q * 8) = l;
  }
}

// ---------------- prep: Wg = gamma * sent_att_w (hi/lo), sg, cb ----------------
__global__ __launch_bounds__(64) void k_prepw(const float* __restrict__ saw,
    const float* __restrict__ sab, const float* __restrict__ gamma,
    const float* __restrict__ beta, short* __restrict__ WGH,
    short* __restrict__ WGL, float* __restrict__ SG, float* __restrict__ CB) {
  const int blk = blockIdx.x;          // c*128 + a
  const int c = blk >> 7;
  const int lane = threadIdx.x;
  const float* wrow = saw + (size_t)blk * DH;
  float sg = 0.f, cbv = 0.f;
  for (int e = lane; e < KP; e += 64) {
    float wg = 0.f;
    if (e < DH) {
      float w = wrow[e];
      wg = w * gamma[c * DH + e];
      sg += wg;
      cbv += beta[c * DH + e] * w;
    }
    short hi = f2bf(wg);
    WGH[(size_t)blk * KP + e] = hi;
    WGL[(size_t)blk * KP + e] = f2bf(wg - bf2f(hi));
  }
#pragma unroll
  for (int off = 32; off; off >>= 1) { sg += __shfl_xor(sg, off); cbv += __shfl_xor(cbv, off); }
  if (lane == 0) { SG[blk] = sg; CB[blk] = cbv + sab[blk]; }
}

// ================= fused XP+GRU kernel (640 threads = 10 waves) =================
// Gate layout is PERMUTED+PADDED: section sec in {0=r,1=z,2=n}, col = sec*160+u,
// real gate = sec*150+u (u<150), cols with u in [150,160) are zero-padded.
// mode 0: blocks [0,40) = GRU(gtbase, XPg); blocks [40,520) = XP(xtbase -> XPx)
// mode 1: all blocks XP ; mode 2: all blocks GRU
__global__ __launch_bounds__(640, 1) void k_xg(int mode, int gtbase, int xtbase,
    const float* __restrict__ XPg, float* __restrict__ XPx,
    const short* __restrict__ DXH, const short* __restrict__ DXL,
    const float* __restrict__ wihf, const float* __restrict__ wihb,
    const float* __restrict__ bihf, const float* __restrict__ bihb,
    const float* __restrict__ whf, const float* __restrict__ whb,
    const float* __restrict__ bhf, const float* __restrict__ bhb,
    const int* __restrict__ perm, const int* __restrict__ Lp,
    __hip_bfloat16* __restrict__ HALL, float* __restrict__ HST) {
  extern __shared__ __align__(16) char smem[];
  const int tid = threadIdx.x, lane = tid & 63, wid = tid >> 6;
  const int l15 = lane & 15, kg = lane >> 4;
  bool isGru; int xpBlk;
  if (mode == 0) { isGru = (int)blockIdx.x < 40; xpBlk = blockIdx.x - 40; }
  else if (mode == 1) { isGru = false; xpBlk = blockIdx.x; }
  else { isGru = true; xpBlk = 0; }

  if (!isGru) {
    // -------- XP body: 160 permuted gate-cols x 32 rows per iter, 8 iters --------
    const int y = xpBlk / 30, sn = xpBlk - y * 30;
    const int s = sn / 3, nt = sn - (sn / 3) * 3;   // sec == nt
    const int c = s >> 1, dir = s & 1;
    const float* W  = (dir ? wihb : wihf) + (size_t)c * G3 * E;
    const float* Bi = (dir ? bihb : bihf) + (size_t)c * G3;
    const int u = wid * 16 + l15;            // 0..159
    const int gwp = nt * 160 + u;            // permuted col
    const bool gv = (u < H);
    const int g = nt * H + u;                // real gate row
    const float biasv = gv ? Bi[g] : 0.f;
    short8v Whi[10], Wlo[10];
#pragma unroll
    for (int sl = 0; sl < 10; sl++) {
      short8v hi{}, lo{};
      if (gv) {
#pragma unroll
        for (int j = 0; j < 8; j++) {
          int k = sl * 32 + kg * 8 + j;
          if (k < E) {
            float w = W[(size_t)g * E + k];
            short h = f2bf(w);
            hi[j] = h; lo[j] = f2bf(w - bf2f(h));
          }
        }
      }
      Whi[sl] = hi; Wlo[sl] = lo;
    }
    short* Ah = (short*)smem;            // 32*LDA
    short* Al = (short*)(smem + 32 * LDA * 2);
    for (int i = 0; i < 8; i++) {
      const int idx = y * 8 + i;           // 0..127
      const int b = idx >> 1, mtile = idx & 1;
      const int L = Lp[b];
      const int pb = perm[b];
      const int t0g = xtbase + mtile * 32;
      for (int f = tid; f < 32 * (KP / 8); f += 640) {
        int r = f / (KP / 8), q = f - r * (KP / 8);
        int tg = t0g + r;
        int src = (dir && tg < L) ? (L - 1 - tg) : tg;
        size_t go = ((size_t)pb * T + src) * KP + q * 8;
        *(short8v*)&Ah[r * LDA + q * 8] = *(const short8v*)(DXH + go);
        *(short8v*)&Al[r * LDA + q * 8] = *(const short8v*)(DXL + go);
      }
      __syncthreads();
      f32x4 acc[2];
#pragma unroll
      for (int m2 = 0; m2 < 2; m2++) acc[m2] = f32x4{biasv, biasv, biasv, biasv};
#pragma unroll
      for (int sl = 0; sl < 10; sl++) {
#pragma unroll
        for (int m2 = 0; m2 < 2; m2++) {
          const int ro = (m2 * 16 + l15) * LDA + sl * 32 + kg * 8;
          short8v ah = *(const short8v*)&Ah[ro];
          short8v al = *(const short8v*)&Al[ro];
          acc[m2] = __builtin_amdgcn_mfma_f32_16x16x32_bf16(ah, Whi[sl], acc[m2], 0, 0, 0);
          acc[m2] = __builtin_amdgcn_mfma_f32_16x16x32_bf16(ah, Wlo[sl], acc[m2], 0, 0, 0);
          acc[m2] = __builtin_amdgcn_mfma_f32_16x16x32_bf16(al, Whi[sl], acc[m2], 0, 0, 0);
        }
      }
      const size_t base = (size_t)(s * B + b) * CHK * G3P;
#pragma unroll
      for (int m2 = 0; m2 < 2; m2++) {
        const int lt = mtile * 32 + m2 * 16 + kg * 4;
        float* xp = XPx + base + (size_t)lt * G3P + gwp;
#pragma unroll
        for (int v = 0; v < 4; v++) xp[(size_t)v * G3P] = acc[m2][v];
      }
      __syncthreads();
    }
    return;
  }

  // -------- GRU body: in-register activation via gate-triple ownership --------
  const int blk = blockIdx.x;         // 0..39
  const int s = blk >> 2, bt = blk & 3;
  const int b0 = bt << 4;
  const int c = s >> 1, dir = s & 1;
  const float* Whh = (dir ? whb : whf) + (size_t)c * G3 * H;
  const float* Bhh = (dir ? bhb : bhf) + (size_t)c * G3;
  short (*hfH)[16][168] = (short(*)[16][168])smem;            // [2][16][168]
  short (*hfL)[16][168] = (short(*)[16][168])(smem + 10752);

  const int u = wid * 16 + l15;        // unit owned by this lane, 0..159
  const bool uLive = (u < H);

  // persistent W: 3 sections (r,z,n) x 5 K-slices, single bf16 (h is hi/lo)
  short8v Wf[3][5];
  float bias3[3];
#pragma unroll
  for (int sec = 0; sec < 3; sec++) {
    bias3[sec] = uLive ? Bhh[sec * H + u] : 0.f;
#pragma unroll
    for (int sl = 0; sl < 5; sl++) {
      short8v w = {};
      if (uLive) {
#pragma unroll
        for (int j = 0; j < 8; j++) {
          int k = sl * 32 + kg * 8 + j;
          if (k < H) w[j] = f2bf(Whh[(size_t)(sec * H + u) * H + k]);
        }
      }
      Wf[sec][sl] = w;
    }
  }

  // per-thread state: 4 batches (kg*4+v) of unit u
  float hq[4];
  int Lq[4];
  size_t xbase[4], ho[4];
#pragma unroll
  for (int v = 0; v < 4; v++) {
    int bg = b0 + kg * 4 + v;
    Lq[v] = Lp[bg];
    xbase[v] = ((size_t)(s * B + bg) * CHK) * G3P + u;
    ho[v] = ((size_t)(c * B + bg) * T) * DH + (size_t)dir * H + u;
    hq[v] = 0.f;
    if (gtbase > 0 && uLive) hq[v] = HST[(size_t)(s * B + bg) * 152 + u];
  }

  // init: zero both h-frag buffers, then write h0 into buf 0
  for (int f = tid; f < 2 * 16 * 168; f += 640) {
    ((short*)hfH)[f] = 0; ((short*)hfL)[f] = 0;
  }
  __syncthreads();
#pragma unroll
  for (int v = 0; v < 4; v++) {
    short hi = f2bf(hq[v]); float rem = hq[v] - bf2f(hi);
    hfH[0][kg * 4 + v][u] = hi;
    hfL[0][kg * 4 + v][u] = f2bf(rem);
  }
  // xp for step 0
  float xcur[3][4];
#pragma unroll
  for (int sec = 0; sec < 3; sec++)
#pragma unroll
    for (int v = 0; v < 4; v++)
      xcur[sec][v] = XPg[xbase[v] + sec * 160];
  __syncthreads();

  for (int ts = 0; ts < CHK; ts++) {
    const int cur = ts & 1;
    // A-frags (batch rows l15) from current buffer
    short8v ah[5], al[5];
#pragma unroll
    for (int sl = 0; sl < 5; sl++) {
      ah[sl] = *(const short8v*)&hfH[cur][l15][sl * 32 + kg * 8];
      al[sl] = *(const short8v*)&hfL[cur][l15][sl * 32 + kg * 8];
    }
    // prefetch next-step xp (consumed after barrier)
    const int tn = (ts + 1 < CHK) ? ts + 1 : ts;
    float xnxt[3][4];
#pragma unroll
    for (int sec = 0; sec < 3; sec++)
#pragma unroll
      for (int v = 0; v < 4; v++)
        xnxt[sec][v] = XPg[xbase[v] + (size_t)tn * G3P + sec * 160];
    // MFMA: gh_{r,z,n} for 16 batches x unit u
    f32x4 acc[3];
#pragma unroll
    for (int sec = 0; sec < 3; sec++)
      acc[sec] = f32x4{bias3[sec], bias3[sec], bias3[sec], bias3[sec]};
#pragma unroll
    for (int sl = 0; sl < 5; sl++) {
#pragma unroll
      for (int sec = 0; sec < 3; sec++) {
        acc[sec] = __builtin_amdgcn_mfma_f32_16x16x32_bf16(ah[sl], Wf[sec][sl], acc[sec], 0, 0, 0);
        acc[sec] = __builtin_amdgcn_mfma_f32_16x16x32_bf16(al[sl], Wf[sec][sl], acc[sec], 0, 0, 0);
      }
    }
    // in-register activation + h update; write next buffer
    const int t = gtbase + ts;
#pragma unroll
    for (int v = 0; v < 4; v++) {
      float r = fast_sig(xcur[0][v] + acc[0][v]);
      float z = fast_sig(xcur[1][v] + acc[1][v]);
      float n = fast_tanh(fmaf(r, acc[2][v], xcur[2][v]));
      float hnew = fmaf(z, hq[v] - n, n);
      if (!uLive) hnew = 0.f;
      hq[v] = hnew;
      short hi = f2bf(hnew); float rem = hnew - bf2f(hi);
      hfH[cur ^ 1][kg * 4 + v][u] = hi;
      hfL[cur ^ 1][kg * 4 + v][u] = f2bf(rem);
      if (uLive) {
        int tout = dir ? ((t < Lq[v]) ? (Lq[v] - 1 - t) : t) : t;
        HALL[ho[v] + (size_t)tout * DH] = __float2bfloat16(hnew);
      }
    }
#pragma unroll
    for (int sec = 0; sec < 3; sec++)
#pragma unroll
      for (int v = 0; v < 4; v++) xcur[sec][v] = xnxt[sec][v];
    bar_lgkm();
  }
  if (uLive) {
#pragma unroll
    for (int v = 0; v < 4; v++)
      HST[(size_t)(s * B + b0 + kg * 4 + v) * 152 + u] = hq[v];
  }
}

// ---------------- K4: LN-folded MFMA fuse, 512 thr, 1 n-tile/wave ----------------
// grid (256, 5): x = b*4 + quarter(4 t-tiles), y = channel
__global__ __launch_bounds__(512) void k_fuse(const __hip_bfloat16* __restrict__ HALL,
    const short* __restrict__ WGH, const short* __restrict__ WGL,
    const float* __restrict__ SG, const float* __restrict__ CB,
    const float* __restrict__ cvw, float* __restrict__ Ebuf) {
  const int c = blockIdx.y;
  const int b = blockIdx.x >> 2, quar = blockIdx.x & 3;
  const int tid = threadIdx.x, lane = tid & 63, wid = tid >> 6;
  const int l15 = lane & 15, kg = lane >> 4;
  __shared__ short hs[32 * LDA];
  __shared__ float mu_s[32], rs_s[32];
  __shared__ float U_s[32][132];

  // persistent Wg fragments: 1 n-tile/wave x 10 slices, hi/lo (80 VGPR)
  const int n = wid * 16 + l15;
  const float sga = SG[c * A + n], cba = CB[c * A + n];
  short8v Wh[10], Wl[10];
#pragma unroll
  for (int sl = 0; sl < 10; sl++) {
    size_t go = ((size_t)(c * A + n)) * KP + sl * 32 + kg * 8;
    Wh[sl] = *(const short8v*)(WGH + go);
    Wl[sl] = *(const short8v*)(WGL + go);
  }
  const int kc = cKC[c], k0c = cK0[c];
  for (int tt = 0; tt < 4; tt++) {
    const int t0 = (quar * 4 + tt) * 32;
    const short* hbase = (const short*)HALL + ((size_t)(c * B + b) * T + t0) * DH;
    for (int f = tid; f < 32 * 80; f += 512) {
      int r = f / 80, g4 = f - r * 80;
      short4v v{};
      if (g4 < 75) v = *(const short4v*)(hbase + (size_t)r * DH + g4 * 4);
      *(short4v*)&hs[r * LDA + g4 * 4] = v;
    }
    __syncthreads();
    {
      int r = tid >> 4, l = tid & 15;
      float sm = 0.f, sq = 0.f;
      for (int e = l; e < DH; e += 16) {
        float v = bf2f(hs[r * LDA + e]); sm += v; sq += v * v;
      }
      sm += __shfl_xor(sm, 1); sm += __shfl_xor(sm, 2); sm += __shfl_xor(sm, 4); sm += __shfl_xor(sm, 8);
      sq += __shfl_xor(sq, 1); sq += __shfl_xor(sq, 2); sq += __shfl_xor(sq, 4); sq += __shfl_xor(sq, 8);
      if (l == 0) {
        float mu = sm * (1.f / 300.f);
        float var = fmaxf(sq * (1.f / 300.f) - mu * mu, 0.f);
        mu_s[r] = mu; rs_s[r] = rsqrtf(var + 1e-5f);
      }
    }
    __syncthreads();
    f32x4 acc[2] = {};
#pragma unroll
    for (int sl = 0; sl < 10; sl++) {
#pragma unroll
      for (int m2 = 0; m2 < 2; m2++) {
        short8v ah = *(const short8v*)&hs[(m2 * 16 + l15) * LDA + sl * 32 + kg * 8];
        acc[m2] = __builtin_amdgcn_mfma_f32_16x16x32_bf16(ah, Wh[sl], acc[m2], 0, 0, 0);
        acc[m2] = __builtin_amdgcn_mfma_f32_16x16x32_bf16(ah, Wl[sl], acc[m2], 0, 0, 0);
      }
    }
#pragma unroll
    for (int m2 = 0; m2 < 2; m2++) {
#pragma unroll
      for (int v = 0; v < 4; v++) {
        int row = m2 * 16 + kg * 4 + v;
        float val = rs_s[row] * acc[m2][v] - mu_s[row] * rs_s[row] * sga + cba;
        U_s[row][n] = fast_tanh(val);
      }
    }
    __syncthreads();
    for (int idx = tid; idx < 32 * kc; idx += 512) {
      int r = idx / kc, kk = idx - r * kc;
      const float* cv = cvw + (size_t)(k0c + kk) * A;
      float e = 0.f;
#pragma unroll 4
      for (int a = 0; a < A; a++) e = fmaf(U_s[r][a], cv[a], e);
      Ebuf[((size_t)(k0c + kk) * B + b) * T + t0 + r] = e;
    }
    __syncthreads();
  }
}

// ---------------- K5: masked softmax over t per (k,b), in-place ----------------
__global__ __launch_bounds__(256) void k_soft(float* __restrict__ Ebuf,
    const int* __restrict__ Lp) {
  const int k = blockIdx.x >> 6, b = blockIdx.x & 63;
  const int L = Lp[b];
  float* er = Ebuf + ((size_t)k * B + b) * T;
  const int tid = threadIdx.x;
  float v0 = (tid < L) ? er[tid] : -1e30f;
  float v1 = (tid + 256 < L) ? er[tid + 256] : -1e30f;
  float mx = fmaxf(v0, v1);
  __shared__ float red[4];
  __shared__ float red2[4];
#pragma unroll
  for (int off = 32; off; off >>= 1) mx = fmaxf(mx, __shfl_xor(mx, off));
  if ((tid & 63) == 0) red[tid >> 6] = mx;
  __syncthreads();
  mx = fmaxf(fmaxf(red[0], red[1]), fmaxf(red[2], red[3]));
  float e0 = (tid < L) ? __expf(v0 - mx) : 0.f;
  float e1 = (tid + 256 < L) ? __expf(v1 - mx) : 0.f;
  float sm = e0 + e1;
#pragma unroll
  for (int off = 32; off; off >>= 1) sm += __shfl_xor(sm, off);
  if ((tid & 63) == 0) red2[tid >> 6] = sm;
  __syncthreads();
  sm = red2[0] + red2[1] + red2[2] + red2[3];
  const float inv = 1.f / sm;
  er[tid] = e0 * inv;
  er[tid + 256] = e1 * inv;
}

// ---------------- K6: docv[k,b,d] = sum_t att[k,b,t] * h4[b,t,d] ----------------
__global__ __launch_bounds__(256) void k_docv(const __hip_bfloat16* __restrict__ HALL,
    const float* __restrict__ ATT, float* __restrict__ DOCV) {
  const int dt = blockIdx.x, b = blockIdx.y;
  const int d0 = dt << 6;
  const int tid = threadIdx.x, tx = tid & 63, ky = tid >> 6;
  const __hip_bfloat16* hb_ = HALL + ((size_t)(4 * B + b) * T) * DH;
  __shared__ float h_s[64][65];
  __shared__ float att_s[30][66];
  float acc[8] = {};
  const int d = d0 + tx;
  for (int t0 = 0; t0 < T; t0 += 64) {
    for (int f = tid; f < 64 * 64; f += 256) {
      int ttt = f >> 6, dl = f & 63;
      h_s[ttt][dl] = (d0 + dl < DH)
          ? __bfloat162float(hb_[(size_t)(t0 + ttt) * DH + d0 + dl]) : 0.f;
    }
    for (int f = tid; f < 30 * 64; f += 256) {
      int kk = f >> 6, ttt = f & 63;
      att_s[kk][ttt] = ATT[((size_t)kk * B + b) * T + t0 + ttt];
    }
    __syncthreads();
    for (int ttt = 0; ttt < 64; ttt++) {
      float hv = h_s[ttt][tx];
#pragma unroll
      for (int i = 0; i < 8; i++) {
        int kk = ky + (i << 2);
        if (kk < 30) acc[i] = fmaf(att_s[kk][ttt], hv, acc[i]);
      }
    }
    __syncthreads();
  }
  if (d < DH) {
#pragma unroll
    for (int i = 0; i < 8; i++) {
      int kk = ky + (i << 2);
      if (kk < 30) DOCV[((size_t)kk * B + b) * DH + d] = acc[i];
    }
  }
}

// ---------------- K7: group attention + output ----------------
__global__ __launch_bounds__(64) void k_group(const float* __restrict__ DOCV,
    const float* __restrict__ gaw, const float* __restrict__ gab,
    const float* __restrict__ gcv, float* __restrict__ out) {
  const int tt = blockIdx.x / B, b = blockIdx.x % B;
  const int lane = threadIdx.x;
  const int c = cTCAT[tt], cnt = cTC[tt], ks = cTS[tt];
  const float* wrow = gaw + ((size_t)c * 64 + lane) * DH;
  const float gbias = gab[c * 64 + lane];
  const float cvl = gcv[tt * 64 + lane];
  float accd[5] = {0, 0, 0, 0, 0};
  float wsum = 0.f;
  for (int n = 0; n < cnt; n++) {
    const float* drow = DOCV + ((size_t)(ks + n) * B + b) * DH;
    float g = 0.f;
    for (int dd = 0; dd < DH; dd++) g = fmaf(drow[dd], wrow[dd], g);
    g += gbias;
    float p = g * cvl;
#pragma unroll
    for (int off = 32; off; off >>= 1) p += __shfl_xor(p, off);
    float w = __expf(tanhf(p));
    wsum += w;
#pragma unroll
    for (int i = 0; i < 5; i++) {
      int dd = lane + (i << 6);
      if (dd < DH) accd[i] = fmaf(w, drow[dd], accd[i]);
    }
  }
  const float inv = 1.f / wsum;
  float* orow = out + ((size_t)tt * B + b) * DH;
#pragma unroll
  for (int i = 0; i < 5; i++) {
    int dd = lane + (i << 6);
    if (dd < DH) orow[dd] = accd[i] * inv;
  }
}

extern "C" void kernel_launch(void* const* d_in, const int* in_sizes, int n_in,
                              void* d_out, int out_size, void* d_ws, size_t ws_size,
                              hipStream_t stream) {
  const float* docs = (const float*)d_in[0];
  const int* lens = (const int*)d_in[1];
  const float* wihf = (const float*)d_in[2];
  const float* whhf = (const float*)d_in[3];
  const float* bihf = (const float*)d_in[4];
  const float* bhhf = (const float*)d_in[5];
  const float* wihb = (const float*)d_in[6];
  const float* whhb = (const float*)d_in[7];
  const float* bihb = (const float*)d_in[8];
  const float* bhhb = (const float*)d_in[9];
  const float* gam = (const float*)d_in[10];
  const float* bet = (const float*)d_in[11];
  const float* saw = (const float*)d_in[12];
  const float* sab = (const float*)d_in[13];
  const float* gaw = (const float*)d_in[14];
  const float* gab = (const float*)d_in[15];
  const float* cvw = (const float*)d_in[16];
  const float* gcv = (const float*)d_in[17];
  float* out = (float*)d_out;

  char* ws = (char*)d_ws;
  size_t off = 0;
  auto alloc = [&](size_t bytes) { size_t o = off; off = (off + bytes + 255) & ~(size_t)255; return o; };
  int* PERM = (int*)(ws + alloc(64 * 4));
  int* LP   = (int*)(ws + alloc(64 * 4));
  __hip_bfloat16* HALL = (__hip_bfloat16*)(ws + alloc((size_t)NC * B * T * DH * 2));
  float* EB   = (float*)(ws + alloc((size_t)NCV * B * T * 4));
  float* DOCV = (float*)(ws + alloc((size_t)NCV * B * DH * 4));
  float* HST  = (float*)(ws + alloc((size_t)640 * 152 * 4));
  short* WGH  = (short*)(ws + alloc((size_t)NC * A * KP * 2));
  short* WGL  = (short*)(ws + alloc((size_t)NC * A * KP * 2));
  float* SG   = (float*)(ws + alloc((size_t)NC * A * 4));
  float* CB   = (float*)(ws + alloc((size_t)NC * A * 4));
  short* DXH  = (short*)(ws + alloc((size_t)B * T * KP * 2));
  short* DXL  = (short*)(ws + alloc((size_t)B * T * KP * 2));
  const size_t xpBytes = (size_t)10 * B * CHK * G3P * 4;   // 78.6 MB
  const bool dbuf = (off + 2 * xpBytes + 512) <= ws_size;
  float* XP0 = (float*)(ws + alloc(xpBytes));
  float* XP1 = dbuf ? (float*)(ws + alloc(xpBytes)) : XP0;

  const int DYN = 32 * LDA * 2 * 2;   // 41984 B (XP staging; GRU needs 21504)
  const int NXP = 480;                // 16 y-tiles * 10 sets * 3 n-tiles

  hipLaunchKernelGGL(k_perm, dim3(1), dim3(64), 0, stream, lens, PERM, LP);
  hipLaunchKernelGGL(k_prepx, dim3(2048), dim3(256), 0, stream, docs, DXH, DXL);
  hipLaunchKernelGGL(k_prepw, dim3(NC * A), dim3(64), 0, stream,
                     saw, sab, gam, bet, WGH, WGL, SG, CB);
  if (dbuf) {
    hipLaunchKernelGGL(k_xg, dim3(NXP), dim3(640), DYN, stream, 1, 0, 0,
                       XP0, XP0, DXH, DXL, wihf, wihb, bihf, bihb,
                       whhf, whhb, bhhf, bhhb, PERM, LP, HALL, HST);
    for (int j = 0; j < 7; j++) {
      float* g = (j & 1) ? XP1 : XP0;
      float* x = (j & 1) ? XP0 : XP1;
      hipLaunchKernelGGL(k_xg, dim3(40 + NXP), dim3(640), DYN, stream, 0,
                         j * CHK, (j + 1) * CHK, g, x, DXH, DXL,
                         wihf, wihb, bihf, bihb, whhf, whhb, bhhf, bhhb,
                         PERM, LP, HALL, HST);
    }
    hipLaunchKernelGGL(k_xg, dim3(40), dim3(640), DYN, stream, 2,
                       7 * CHK, 0, XP1, XP1, DXH, DXL,
                       wihf, wihb, bihf, bihb, whhf, whhb, bhhf, bhhb,
                       PERM, LP, HALL, HST);
  } else {
    for (int j = 0; j < 8; j++) {
      hipLaunchKernelGGL(k_xg, dim3(NXP), dim3(640), DYN, stream, 1,
                         0, j * CHK, XP0, XP0, DXH, DXL,
                         wihf, wihb, bihf, bihb, whhf, whhb, bhhf, bhhb,
                         PERM, LP, HALL, HST);
      hipLaunchKernelGGL(k_xg, dim3(40), dim3(640), DYN, stream, 2,
                         j * CHK, 0, XP0, XP0, DXH, DXL,
                         wihf, wihb, bihf, bihb, whhf, whhb, bhhf, bhhb,
                         PERM, LP, HALL, HST);
    }
  }
  hipLaunchKernelGGL(k_fuse, dim3(256, 5), dim3(512), 0, stream,
                     HALL, WGH, WGL, SG, CB, cvw, EB);
  hipLaunchKernelGGL(k_soft, dim3(1920), dim3(256), 0, stream, EB, LP);
  hipLaunchKernelGGL(k_docv, dim3(5, 64), dim3(256), 0, stream, HALL, EB, DOCV);
  hipLaunchKernelGGL(k_group, dim3(576), dim3(64), 0, stream, DOCV, gaw, gab, gcv, out);
}

// Round 7
// 1749.687 us; speedup vs baseline: 4.1759x; 1.0423x over previous
//
#include <hip/hip_runtime.h>
#include <hip/hip_bf16.h>
#include <math.h>

#define B   64
#define T   512
#define E   300
#define H   150
#define G3  450   // 3*H
#define DH  300   // 2*H
#define A   128
#define NC  5
#define NCV 30
#define KP  320   // padded K for E/DH (10 slices of 32)
#define G3P 480   // permuted/padded gate dim: 3 sections of 160
#define LDA 328   // LDS row stride in shorts
#define CHK 64    // T-chunk for the fused xp/gru pipeline

__constant__ int cK0[NC]  = {0,9,12,18,24};
__constant__ int cKC[NC]  = {9,3,6,6,6};
__constant__ int cTS[9]   = {0,3,6,9,12,18,21,24,27};
__constant__ int cTC[9]   = {3,3,3,3,6,3,3,3,3};
__constant__ int cTCAT[9] = {0,0,0,1,2,3,3,4,4};

typedef __attribute__((ext_vector_type(8))) short short8v;
typedef __attribute__((ext_vector_type(4))) short short4v;
typedef __attribute__((ext_vector_type(4))) float f32x4;

__device__ __forceinline__ short f2bf(float v) {
  unsigned u = __builtin_bit_cast(unsigned, v);
  u += 0x7FFFu + ((u >> 16) & 1u);
  return (short)(u >> 16);
}
__device__ __forceinline__ float bf2f(short s) {
  unsigned u = ((unsigned)(unsigned short)s) << 16;
  return __builtin_bit_cast(float, u);
}
// barrier that does NOT drain vmcnt; LDS producer->consumer needs lgkm only.
__device__ __forceinline__ void bar_lgkm() {
  asm volatile("s_waitcnt lgkmcnt(0)" ::: "memory");
  __builtin_amdgcn_s_barrier();
  __builtin_amdgcn_sched_barrier(0);
}
__device__ __forceinline__ float fast_sig(float x) {
  return __builtin_amdgcn_rcpf(1.f + __expf(-x));
}
__device__ __forceinline__ float fast_tanh(float x) {
  x = fminf(fmaxf(x, -15.f), 15.f);
  float ex = __expf(2.f * x);
  return (ex - 1.f) * __builtin_amdgcn_rcpf(ex + 1.f);
}

// ---------------- K1: stable argsort(-lengths) ----------------
__global__ void k_perm(const int* __restrict__ len, int* __restrict__ perm,
                       int* __restrict__ Lp) {
  __shared__ int sp[B];
  int b = threadIdx.x;
  int lb = len[b];
  int rank = 0;
  for (int j = 0; j < B; j++) {
    int lj = len[j];
    rank += (lj > lb) || (lj == lb && j < b);
  }
  sp[rank] = b;
  __syncthreads();
  perm[b] = sp[b];
  Lp[b] = len[sp[b]];
}

// ---------------- prep: docs -> bf16 hi/lo, padded to KP ----------------
__global__ __launch_bounds__(256) void k_prepx(const float* __restrict__ docs,
    short* __restrict__ DXH, short* __restrict__ DXL) {
  const int total = B * T * (KP / 8);
  for (int i = blockIdx.x * 256 + threadIdx.x; i < total; i += gridDim.x * 256) {
    int bt = i / (KP / 8), q = i - bt * (KP / 8);
    const float* src = docs + (size_t)bt * E + q * 8;
    short8v h{}, l{};
#pragma unroll
    for (int j = 0; j < 8; j++) {
      int e = q * 8 + j;
      float v = (e < E) ? src[j] : 0.f;
      short hi = f2bf(v);
      h[j] = hi; l[j] = f2bf(v - bf2f(hi));
    }
    *(short8v*)(DXH + (size_t)bt * KP + q * 8) = h;
    *(short8v*)(DXL + (size_t)bt * KP + q * 8) = l;
  }
}

// ---------------- prep: Wg = gamma * sent_att_w (hi/lo), sg, cb ----------------
__global__ __launch_bounds__(64) void k_prepw(const float* __restrict__ saw,
    const float* __restrict__ sab, const float* __restrict__ gamma,
    const float* __restrict__ beta, short* __restrict__ WGH,
    short* __restrict__ WGL, float* __restrict__ SG, float* __restrict__ CB) {
  const int blk = blockIdx.x;          // c*128 + a
  const int c = blk >> 7;
  const int lane = threadIdx.x;
  const float* wrow = saw + (size_t)blk * DH;
  float sg = 0.f, cbv = 0.f;
  for (int e = lane; e < KP; e += 64) {
    float wg = 0.f;
    if (e < DH) {
      float w = wrow[e];
      wg = w * gamma[c * DH + e];
      sg += wg;
      cbv += beta[c * DH + e] * w;
    }
    short hi = f2bf(wg);
    WGH[(size_t)blk * KP + e] = hi;
    WGL[(size_t)blk * KP + e] = f2bf(wg - bf2f(hi));
  }
#pragma unroll
  for (int off = 32; off; off >>= 1) { sg += __shfl_xor(sg, off); cbv += __shfl_xor(cbv, off); }
  if (lane == 0) { SG[blk] = sg; CB[blk] = cbv + sab[blk]; }
}

// ================= fused XP+GRU kernel (640 threads = 10 waves) =================
// Gate layout PERMUTED+PADDED: sec in {0=r,1=z,2=n}, col = sec*160+u.
// MODE 0: blocks [0,40) GRU(gtbase,XPg); [40,..) XP(xtbase->XPx). MODE 1: XP. MODE 2: GRU.
#define GRU_STEP(TS, CUR, XC)                                                   \
  do {                                                                          \
    short8v ah_[5], al_[5];                                                     \
    _Pragma("unroll") for (int sl = 0; sl < 5; sl++) {                          \
      ah_[sl] = *(const short8v*)&hfH[CUR][l15][sl * 32 + kg * 8];              \
      al_[sl] = *(const short8v*)&hfL[CUR][l15][sl * 32 + kg * 8];              \
    }                                                                           \
    const int tpre = ((TS) + 2 < CHK) ? (TS) + 2 : CHK - 1;                     \
    float xN[3][4];                                                             \
    _Pragma("unroll") for (int sec = 0; sec < 3; sec++)                         \
      _Pragma("unroll") for (int v = 0; v < 4; v++)                             \
        xN[sec][v] = XPg[xbase[v] + (size_t)tpre * G3P + sec * 160];            \
    f32x4 acc[3];                                                               \
    _Pragma("unroll") for (int sec = 0; sec < 3; sec++)                         \
      acc[sec] = f32x4{bias3[sec], bias3[sec], bias3[sec], bias3[sec]};         \
    _Pragma("unroll") for (int sl = 0; sl < 5; sl++) {                          \
      _Pragma("unroll") for (int sec = 0; sec < 3; sec++) {                     \
        acc[sec] = __builtin_amdgcn_mfma_f32_16x16x32_bf16(ah_[sl], Wf[sec][sl], acc[sec], 0, 0, 0); \
        acc[sec] = __builtin_amdgcn_mfma_f32_16x16x32_bf16(al_[sl], Wf[sec][sl], acc[sec], 0, 0, 0); \
      }                                                                         \
    }                                                                           \
    const int t = gtbase + (TS);                                                \
    _Pragma("unroll") for (int v = 0; v < 4; v++) {                             \
      float r = fast_sig(XC[0][v] + acc[0][v]);                                 \
      float z = fast_sig(XC[1][v] + acc[1][v]);                                 \
      float n = fast_tanh(fmaf(r, acc[2][v], XC[2][v]));                        \
      float hnew = fmaf(z, hq[v] - n, n);                                       \
      if (!uLive) hnew = 0.f;                                                   \
      hq[v] = hnew;                                                             \
      short hi = f2bf(hnew); float rem = hnew - bf2f(hi);                       \
      hfH[(CUR) ^ 1][kg * 4 + v][u] = hi;                                       \
      hfL[(CUR) ^ 1][kg * 4 + v][u] = f2bf(rem);                                \
      if (uLive) {                                                              \
        int tout = dir ? ((t < Lq[v]) ? (Lq[v] - 1 - t) : t) : t;               \
        HALL[ho[v] + (size_t)tout * DH] = __float2bfloat16(hnew);               \
      }                                                                         \
    }                                                                           \
    _Pragma("unroll") for (int sec = 0; sec < 3; sec++)                         \
      _Pragma("unroll") for (int v = 0; v < 4; v++) XC[sec][v] = xN[sec][v];    \
    bar_lgkm();                                                                 \
  } while (0)

template<int MODE>
__global__ __launch_bounds__(640, 1) void k_xg(int gtbase, int xtbase,
    const float* __restrict__ XPg, float* __restrict__ XPx,
    const short* __restrict__ DXH, const short* __restrict__ DXL,
    const float* __restrict__ wihf, const float* __restrict__ wihb,
    const float* __restrict__ bihf, const float* __restrict__ bihb,
    const float* __restrict__ whf, const float* __restrict__ whb,
    const float* __restrict__ bhf, const float* __restrict__ bhb,
    const int* __restrict__ perm, const int* __restrict__ Lp,
    __hip_bfloat16* __restrict__ HALL, float* __restrict__ HST) {
  extern __shared__ __align__(16) char smem[];
  const int tid = threadIdx.x, lane = tid & 63, wid = tid >> 6;
  const int l15 = lane & 15, kg = lane >> 4;
  bool isGru; int xpBlk;
  if (MODE == 0) { isGru = (int)blockIdx.x < 40; xpBlk = blockIdx.x - 40; }
  else if (MODE == 1) { isGru = false; xpBlk = blockIdx.x; }
  else { isGru = true; xpBlk = 0; }

  if (!isGru) {
    // XCD-grouped mapping: xcd owns y in {2*xcd, 2*xcd+1}; 30 (s,nt) sharers
    // of a y-group land on the SAME XCD -> A-tile served from its L2.
    const int xcd = xpBlk & 7, i0 = xpBlk >> 3;          // i0 in [0,60)
    const int y = 2 * xcd + (i0 >= 30 ? 1 : 0);
    const int sn = (i0 >= 30) ? i0 - 30 : i0;
    const int s = sn / 3, nt = sn - (sn / 3) * 3;
    const int c = s >> 1, dir = s & 1;
    const float* W  = (dir ? wihb : wihf) + (size_t)c * G3 * E;
    const float* Bi = (dir ? bihb : bihf) + (size_t)c * G3;
    const int u = wid * 16 + l15;            // 0..159
    const int gwp = nt * 160 + u;
    const bool gv = (u < H);
    const int g = nt * H + u;
    const float biasv = gv ? Bi[g] : 0.f;
    short8v Whi[10], Wlo[10];
#pragma unroll
    for (int sl = 0; sl < 10; sl++) {
      short8v hi{}, lo{};
      if (gv) {
#pragma unroll
        for (int j = 0; j < 8; j++) {
          int k = sl * 32 + kg * 8 + j;
          if (k < E) {
            float w = W[(size_t)g * E + k];
            short h = f2bf(w);
            hi[j] = h; lo[j] = f2bf(w - bf2f(h));
          }
        }
      }
      Whi[sl] = hi; Wlo[sl] = lo;
    }
    short* Ah = (short*)smem;
    short* Al = (short*)(smem + 32 * LDA * 2);
    for (int it = 0; it < 8; it++) {
      const int idx = y * 8 + it;
      const int b = idx >> 1, mtile = idx & 1;
      const int L = Lp[b];
      const int pb = perm[b];
      const int t0g = xtbase + mtile * 32;
      for (int f = tid; f < 32 * (KP / 8); f += 640) {
        int r = f / (KP / 8), q = f - r * (KP / 8);
        int tg = t0g + r;
        int src = (dir && tg < L) ? (L - 1 - tg) : tg;
        size_t go = ((size_t)pb * T + src) * KP + q * 8;
        *(short8v*)&Ah[r * LDA + q * 8] = *(const short8v*)(DXH + go);
        *(short8v*)&Al[r * LDA + q * 8] = *(const short8v*)(DXL + go);
      }
      __syncthreads();
      // 4 independent MFMA chains (slice parity x m2)
      f32x4 acc0[2], acc1[2];
#pragma unroll
      for (int m2 = 0; m2 < 2; m2++) {
        acc0[m2] = f32x4{biasv, biasv, biasv, biasv};
        acc1[m2] = f32x4{0.f, 0.f, 0.f, 0.f};
      }
#pragma unroll
      for (int sl = 0; sl < 10; sl += 2) {
#pragma unroll
        for (int m2 = 0; m2 < 2; m2++) {
          const int ro0 = (m2 * 16 + l15) * LDA + sl * 32 + kg * 8;
          short8v ah0 = *(const short8v*)&Ah[ro0];
          short8v al0 = *(const short8v*)&Al[ro0];
          acc0[m2] = __builtin_amdgcn_mfma_f32_16x16x32_bf16(ah0, Whi[sl], acc0[m2], 0, 0, 0);
          acc0[m2] = __builtin_amdgcn_mfma_f32_16x16x32_bf16(ah0, Wlo[sl], acc0[m2], 0, 0, 0);
          acc0[m2] = __builtin_amdgcn_mfma_f32_16x16x32_bf16(al0, Whi[sl], acc0[m2], 0, 0, 0);
          const int ro1 = ro0 + 32;
          short8v ah1 = *(const short8v*)&Ah[ro1];
          short8v al1 = *(const short8v*)&Al[ro1];
          acc1[m2] = __builtin_amdgcn_mfma_f32_16x16x32_bf16(ah1, Whi[sl + 1], acc1[m2], 0, 0, 0);
          acc1[m2] = __builtin_amdgcn_mfma_f32_16x16x32_bf16(ah1, Wlo[sl + 1], acc1[m2], 0, 0, 0);
          acc1[m2] = __builtin_amdgcn_mfma_f32_16x16x32_bf16(al1, Whi[sl + 1], acc1[m2], 0, 0, 0);
        }
      }
      const size_t base = (size_t)(s * B + b) * CHK * G3P;
#pragma unroll
      for (int m2 = 0; m2 < 2; m2++) {
        f32x4 acc = acc0[m2] + acc1[m2];
        const int lt = mtile * 32 + m2 * 16 + kg * 4;
        float* xp = XPx + base + (size_t)lt * G3P + gwp;
#pragma unroll
        for (int v = 0; v < 4; v++) xp[(size_t)v * G3P] = acc[v];
      }
      __syncthreads();
    }
    return;
  }

  // -------- GRU body: in-register activation, depth-2 xp prefetch --------
  const int blk = blockIdx.x;         // 0..39
  const int s = blk >> 2, bt = blk & 3;
  const int b0 = bt << 4;
  const int c = s >> 1, dir = s & 1;
  const float* Whh = (dir ? whb : whf) + (size_t)c * G3 * H;
  const float* Bhh = (dir ? bhb : bhf) + (size_t)c * G3;
  short (*hfH)[16][168] = (short(*)[16][168])smem;
  short (*hfL)[16][168] = (short(*)[16][168])(smem + 10752);

  const int u = wid * 16 + l15;
  const bool uLive = (u < H);

  short8v Wf[3][5];
  float bias3[3];
#pragma unroll
  for (int sec = 0; sec < 3; sec++) {
    bias3[sec] = uLive ? Bhh[sec * H + u] : 0.f;
#pragma unroll
    for (int sl = 0; sl < 5; sl++) {
      short8v w = {};
      if (uLive) {
#pragma unroll
        for (int j = 0; j < 8; j++) {
          int k = sl * 32 + kg * 8 + j;
          if (k < H) w[j] = f2bf(Whh[(size_t)(sec * H + u) * H + k]);
        }
      }
      Wf[sec][sl] = w;
    }
  }

  float hq[4];
  int Lq[4];
  size_t xbase[4], ho[4];
#pragma unroll
  for (int v = 0; v < 4; v++) {
    int bg = b0 + kg * 4 + v;
    Lq[v] = Lp[bg];
    xbase[v] = ((size_t)(s * B + bg) * CHK) * G3P + u;
    ho[v] = ((size_t)(c * B + bg) * T) * DH + (size_t)dir * H + u;
    hq[v] = 0.f;
    if (gtbase > 0 && uLive) hq[v] = HST[(size_t)(s * B + bg) * 152 + u];
  }

  for (int f = tid; f < 2 * 16 * 168; f += 640) {
    ((short*)hfH)[f] = 0; ((short*)hfL)[f] = 0;
  }
  __syncthreads();
#pragma unroll
  for (int v = 0; v < 4; v++) {
    short hi = f2bf(hq[v]); float rem = hq[v] - bf2f(hi);
    hfH[0][kg * 4 + v][u] = hi;
    hfL[0][kg * 4 + v][u] = f2bf(rem);
  }
  float xA[3][4], xB[3][4];
#pragma unroll
  for (int sec = 0; sec < 3; sec++)
#pragma unroll
    for (int v = 0; v < 4; v++) {
      xA[sec][v] = XPg[xbase[v] + sec * 160];
      xB[sec][v] = XPg[xbase[v] + (size_t)G3P + sec * 160];
    }
  __syncthreads();

  for (int ts = 0; ts < CHK; ts += 2) {
    GRU_STEP(ts, 0, xA);
    GRU_STEP(ts + 1, 1, xB);
  }
  if (uLive) {
#pragma unroll
    for (int v = 0; v < 4; v++)
      HST[(size_t)(s * B + b0 + kg * 4 + v) * 152 + u] = hq[v];
  }
}

// ---------------- K4: LN-folded MFMA fuse, 512 thr, 1 n-tile/wave ----------------
__global__ __launch_bounds__(512) void k_fuse(const __hip_bfloat16* __restrict__ HALL,
    const short* __restrict__ WGH, const short* __restrict__ WGL,
    const float* __restrict__ SG, const float* __restrict__ CB,
    const float* __restrict__ cvw, float* __restrict__ Ebuf) {
  const int c = blockIdx.y;
  const int b = blockIdx.x >> 2, quar = blockIdx.x & 3;
  const int tid = threadIdx.x, lane = tid & 63, wid = tid >> 6;
  const int l15 = lane & 15, kg = lane >> 4;
  __shared__ short hs[32 * LDA];
  __shared__ float mu_s[32], rs_s[32];
  __shared__ float U_s[32][132];

  const int n = wid * 16 + l15;
  const float sga = SG[c * A + n], cba = CB[c * A + n];
  short8v Wh[10], Wl[10];
#pragma unroll
  for (int sl = 0; sl < 10; sl++) {
    size_t go = ((size_t)(c * A + n)) * KP + sl * 32 + kg * 8;
    Wh[sl] = *(const short8v*)(WGH + go);
    Wl[sl] = *(const short8v*)(WGL + go);
  }
  const int kc = cKC[c], k0c = cK0[c];
  for (int tt = 0; tt < 4; tt++) {
    const int t0 = (quar * 4 + tt) * 32;
    const short* hbase = (const short*)HALL + ((size_t)(c * B + b) * T + t0) * DH;
    for (int f = tid; f < 32 * 80; f += 512) {
      int r = f / 80, g4 = f - r * 80;
      short4v v{};
      if (g4 < 75) v = *(const short4v*)(hbase + (size_t)r * DH + g4 * 4);
      *(short4v*)&hs[r * LDA + g4 * 4] = v;
    }
    __syncthreads();
    {
      int r = tid >> 4, l = tid & 15;
      float sm = 0.f, sq = 0.f;
      for (int e = l; e < DH; e += 16) {
        float v = bf2f(hs[r * LDA + e]); sm += v; sq += v * v;
      }
      sm += __shfl_xor(sm, 1); sm += __shfl_xor(sm, 2); sm += __shfl_xor(sm, 4); sm += __shfl_xor(sm, 8);
      sq += __shfl_xor(sq, 1); sq += __shfl_xor(sq, 2); sq += __shfl_xor(sq, 4); sq += __shfl_xor(sq, 8);
      if (l == 0) {
        float mu = sm * (1.f / 300.f);
        float var = fmaxf(sq * (1.f / 300.f) - mu * mu, 0.f);
        mu_s[r] = mu; rs_s[r] = rsqrtf(var + 1e-5f);
      }
    }
    __syncthreads();
    // split hi/lo accumulation chains (4 independent chains)
    f32x4 acch[2] = {}, accl[2] = {};
#pragma unroll
    for (int sl = 0; sl < 10; sl++) {
#pragma unroll
      for (int m2 = 0; m2 < 2; m2++) {
        short8v ah = *(const short8v*)&hs[(m2 * 16 + l15) * LDA + sl * 32 + kg * 8];
        acch[m2] = __builtin_amdgcn_mfma_f32_16x16x32_bf16(ah, Wh[sl], acch[m2], 0, 0, 0);
        accl[m2] = __builtin_amdgcn_mfma_f32_16x16x32_bf16(ah, Wl[sl], accl[m2], 0, 0, 0);
      }
    }
#pragma unroll
    for (int m2 = 0; m2 < 2; m2++) {
      f32x4 acc = acch[m2] + accl[m2];
#pragma unroll
      for (int v = 0; v < 4; v++) {
        int row = m2 * 16 + kg * 4 + v;
        float val = rs_s[row] * acc[v] - mu_s[row] * rs_s[row] * sga + cba;
        U_s[row][n] = fast_tanh(val);
      }
    }
    __syncthreads();
    for (int idx = tid; idx < 32 * kc; idx += 512) {
      int r = idx / kc, kk = idx - r * kc;
      const float* cv = cvw + (size_t)(k0c + kk) * A;
      float e = 0.f;
#pragma unroll 4
      for (int a = 0; a < A; a++) e = fmaf(U_s[r][a], cv[a], e);
      Ebuf[((size_t)(k0c + kk) * B + b) * T + t0 + r] = e;
    }
    __syncthreads();
  }
}

// ---------------- K5: masked softmax over t per (k,b), in-place ----------------
__global__ __launch_bounds__(256) void k_soft(float* __restrict__ Ebuf,
    const int* __restrict__ Lp) {
  const int k = blockIdx.x >> 6, b = blockIdx.x & 63;
  const int L = Lp[b];
  float* er = Ebuf + ((size_t)k * B + b) * T;
  const int tid = threadIdx.x;
  float v0 = (tid < L) ? er[tid] : -1e30f;
  float v1 = (tid + 256 < L) ? er[tid + 256] : -1e30f;
  float mx = fmaxf(v0, v1);
  __shared__ float red[4];
  __shared__ float red2[4];
#pragma unroll
  for (int off = 32; off; off >>= 1) mx = fmaxf(mx, __shfl_xor(mx, off));
  if ((tid & 63) == 0) red[tid >> 6] = mx;
  __syncthreads();
  mx = fmaxf(fmaxf(red[0], red[1]), fmaxf(red[2], red[3]));
  float e0 = (tid < L) ? __expf(v0 - mx) : 0.f;
  float e1 = (tid + 256 < L) ? __expf(v1 - mx) : 0.f;
  float sm = e0 + e1;
#pragma unroll
  for (int off = 32; off; off >>= 1) sm += __shfl_xor(sm, off);
  if ((tid & 63) == 0) red2[tid >> 6] = sm;
  __syncthreads();
  sm = red2[0] + red2[1] + red2[2] + red2[3];
  const float inv = 1.f / sm;
  er[tid] = e0 * inv;
  er[tid + 256] = e1 * inv;
}

// ---------------- K6: docv partials over t-slices: grid (5, 64, 8) ----------------
__global__ __launch_bounds__(256) void k_docv(const __hip_bfloat16* __restrict__ HALL,
    const float* __restrict__ ATT, float* __restrict__ DOCVP) {
  const int dt = blockIdx.x, b = blockIdx.y, tp = blockIdx.z;
  const int d0 = dt << 6, t0 = tp << 6;
  const int tid = threadIdx.x, tx = tid & 63, ky = tid >> 6;
  const __hip_bfloat16* hb_ = HALL + ((size_t)(4 * B + b) * T + t0) * DH;
  __shared__ float h_s[64][65];
  __shared__ float att_s[30][66];
  float acc[8] = {};
  const int d = d0 + tx;
  for (int f = tid; f < 64 * 64; f += 256) {
    int ttt = f >> 6, dl = f & 63;
    h_s[ttt][dl] = (d0 + dl < DH)
        ? __bfloat162float(hb_[(size_t)ttt * DH + d0 + dl]) : 0.f;
  }
  for (int f = tid; f < 30 * 64; f += 256) {
    int kk = f >> 6, ttt = f & 63;
    att_s[kk][ttt] = ATT[((size_t)kk * B + b) * T + t0 + ttt];
  }
  __syncthreads();
  for (int ttt = 0; ttt < 64; ttt++) {
    float hv = h_s[ttt][tx];
#pragma unroll
    for (int i = 0; i < 8; i++) {
      int kk = ky + (i << 2);
      if (kk < 30) acc[i] = fmaf(att_s[kk][ttt], hv, acc[i]);
    }
  }
  if (d < DH) {
#pragma unroll
    for (int i = 0; i < 8; i++) {
      int kk = ky + (i << 2);
      if (kk < 30)
        DOCVP[((size_t)(tp * NCV + kk) * B + b) * DH + d] = acc[i];
    }
  }
}

// ---------------- reduce 8 docv partials (float4) ----------------
__global__ __launch_bounds__(256) void k_dred(const float* __restrict__ DOCVP,
    float* __restrict__ DOCV) {
  const int n4 = NCV * B * DH / 4;   // 144000
  int i = blockIdx.x * 256 + threadIdx.x;
  if (i < n4) {
    f32x4 s = {};
#pragma unroll
    for (int p = 0; p < 8; p++) s += ((const f32x4*)DOCVP)[(size_t)p * n4 + i];
    ((f32x4*)DOCV)[i] = s;
  }
}

// ---------------- K7: group attention + output ----------------
__global__ __launch_bounds__(64) void k_group(const float* __restrict__ DOCV,
    const float* __restrict__ gaw, const float* __restrict__ gab,
    const float* __restrict__ gcv, float* __restrict__ out) {
  const int tt = blockIdx.x / B, b = blockIdx.x % B;
  const int lane = threadIdx.x;
  const int c = cTCAT[tt], cnt = cTC[tt], ks = cTS[tt];
  const float* wrow = gaw + ((size_t)c * 64 + lane) * DH;
  const float gbias = gab[c * 64 + lane];
  const float cvl = gcv[tt * 64 + lane];
  float accd[5] = {0, 0, 0, 0, 0};
  float wsum = 0.f;
  for (int n = 0; n < cnt; n++) {
    const float* drow = DOCV + ((size_t)(ks + n) * B + b) * DH;
    float g = 0.f;
    for (int dd = 0; dd < DH; dd++) g = fmaf(drow[dd], wrow[dd], g);
    g += gbias;
    float p = g * cvl;
#pragma unroll
    for (int off = 32; off; off >>= 1) p += __shfl_xor(p, off);
    float w = __expf(tanhf(p));
    wsum += w;
#pragma unroll
    for (int i = 0; i < 5; i++) {
      int dd = lane + (i << 6);
      if (dd < DH) accd[i] = fmaf(w, drow[dd], accd[i]);
    }
  }
  const float inv = 1.f / wsum;
  float* orow = out + ((size_t)tt * B + b) * DH;
#pragma unroll
  for (int i = 0; i < 5; i++) {
    int dd = lane + (i << 6);
    if (dd < DH) orow[dd] = accd[i] * inv;
  }
}

extern "C" void kernel_launch(void* const* d_in, const int* in_sizes, int n_in,
                              void* d_out, int out_size, void* d_ws, size_t ws_size,
                              hipStream_t stream) {
  const float* docs = (const float*)d_in[0];
  const int* lens = (const int*)d_in[1];
  const float* wihf = (const float*)d_in[2];
  const float* whhf = (const float*)d_in[3];
  const float* bihf = (const float*)d_in[4];
  const float* bhhf = (const float*)d_in[5];
  const float* wihb = (const float*)d_in[6];
  const float* whhb = (const float*)d_in[7];
  const float* bihb = (const float*)d_in[8];
  const float* bhhb = (const float*)d_in[9];
  const float* gam = (const float*)d_in[10];
  const float* bet = (const float*)d_in[11];
  const float* saw = (const float*)d_in[12];
  const float* sab = (const float*)d_in[13];
  const float* gaw = (const float*)d_in[14];
  const float* gab = (const float*)d_in[15];
  const float* cvw = (const float*)d_in[16];
  const float* gcv = (const float*)d_in[17];
  float* out = (float*)d_out;

  char* ws = (char*)d_ws;
  size_t off = 0;
  auto alloc = [&](size_t bytes) { size_t o = off; off = (off + bytes + 255) & ~(size_t)255; return o; };
  int* PERM = (int*)(ws + alloc(64 * 4));
  int* LP   = (int*)(ws + alloc(64 * 4));
  __hip_bfloat16* HALL = (__hip_bfloat16*)(ws + alloc((size_t)NC * B * T * DH * 2));
  float* EB    = (float*)(ws + alloc((size_t)NCV * B * T * 4));
  float* DOCV  = (float*)(ws + alloc((size_t)NCV * B * DH * 4));
  float* DOCVP = (float*)(ws + alloc((size_t)8 * NCV * B * DH * 4));
  float* HST   = (float*)(ws + alloc((size_t)640 * 152 * 4));
  short* WGH   = (short*)(ws + alloc((size_t)NC * A * KP * 2));
  short* WGL   = (short*)(ws + alloc((size_t)NC * A * KP * 2));
  float* SG    = (float*)(ws + alloc((size_t)NC * A * 4));
  float* CB    = (float*)(ws + alloc((size_t)NC * A * 4));
  short* DXH   = (short*)(ws + alloc((size_t)B * T * KP * 2));
  short* DXL   = (short*)(ws + alloc((size_t)B * T * KP * 2));
  const size_t xpBytes = (size_t)10 * B * CHK * G3P * 4;   // 78.6 MB
  const bool dbuf = (off + 2 * xpBytes + 512) <= ws_size;
  float* XP0 = (float*)(ws + alloc(xpBytes));
  float* XP1 = dbuf ? (float*)(ws + alloc(xpBytes)) : XP0;

  const int DYN = 32 * LDA * 2 * 2;   // 41984 B
  const int NXP = 480;

  hipLaunchKernelGGL(k_perm, dim3(1), dim3(64), 0, stream, lens, PERM, LP);
  hipLaunchKernelGGL(k_prepx, dim3(2048), dim3(256), 0, stream, docs, DXH, DXL);
  hipLaunchKernelGGL(k_prepw, dim3(NC * A), dim3(64), 0, stream,
                     saw, sab, gam, bet, WGH, WGL, SG, CB);
  if (dbuf) {
    k_xg<1><<<dim3(NXP), dim3(640), DYN, stream>>>(0, 0,
        XP0, XP0, DXH, DXL, wihf, wihb, bihf, bihb,
        whhf, whhb, bhhf, bhhb, PERM, LP, HALL, HST);
    for (int j = 0; j < 7; j++) {
      float* g = (j & 1) ? XP1 : XP0;
      float* x = (j & 1) ? XP0 : XP1;
      k_xg<0><<<dim3(40 + NXP), dim3(640), DYN, stream>>>(j * CHK, (j + 1) * CHK,
          g, x, DXH, DXL, wihf, wihb, bihf, bihb,
          whhf, whhb, bhhf, bhhb, PERM, LP, HALL, HST);
    }
    k_xg<2><<<dim3(40), dim3(640), DYN, stream>>>(7 * CHK, 0,
        XP1, XP1, DXH, DXL, wihf, wihb, bihf, bihb,
        whhf, whhb, bhhf, bhhb, PERM, LP, HALL, HST);
  } else {
    for (int j = 0; j < 8; j++) {
      k_xg<1><<<dim3(NXP), dim3(640), DYN, stream>>>(0, j * CHK,
          XP0, XP0, DXH, DXL, wihf, wihb, bihf, bihb,
          whhf, whhb, bhhf, bhhb, PERM, LP, HALL, HST);
      k_xg<2><<<dim3(40), dim3(640), DYN, stream>>>(j * CHK, 0,
          XP0, XP0, DXH, DXL, wihf, wihb, bihf, bihb,
          whhf, whhb, bhhf, bhhb, PERM, LP, HALL, HST);
    }
  }
  hipLaunchKernelGGL(k_fuse, dim3(256, 5), dim3(512), 0, stream,
                     HALL, WGH, WGL, SG, CB, cvw, EB);
  hipLaunchKernelGGL(k_soft, dim3(1920), dim3(256), 0, stream, EB, LP);
  hipLaunchKernelGGL(k_docv, dim3(5, 64, 8), dim3(256), 0, stream, HALL, EB, DOCVP);
  hipLaunchKernelGGL(k_dred, dim3((NCV * B * DH / 4 + 255) / 256), dim3(256), 0, stream,
                     DOCVP, DOCV);
  hipLaunchKernelGGL(k_group, dim3(576), dim3(64), 0, stream, DOCV, gaw, gab, gcv, out);
}